// Round 1
// baseline (2175.608 us; speedup 1.0000x reference)
//
#include <hip/hip_runtime.h>
#include <math.h>

#define Q_NODES 100000
#define S_NODES 100000
#define N_EDGES 3200000
#define HIDDEN 64
#define OUT_DIM 128

// Workspace layout (bytes):
//   [0,           4800000)  acc   : 12 * Q floats (SoA: cnt,sumd,sumd2,sx,sy,sz,xx,xy,xz,yy,yz,zz)
//   [4800000,     4800144)  stats : 18 doubles (sum[9], sumsq[9])
//   [4800144,     4800224)  norm  : 18 floats (mean[9], inv_std[9]) + pad
//   [4800224,     8400224)  feats : 9 * Q floats (SoA)
#define ACC_OFF    0
#define STATS_OFF  4800000
#define NORM_OFF   4800144
#define FEATS_OFF  4800224
#define ZERO_BYTES 4800144   // acc + stats must be zeroed each launch

__device__ __forceinline__ void atomAddF(float* p, float v) {
#if defined(__gfx950__) || defined(__gfx942__) || defined(__gfx90a__)
    unsafeAtomicAdd(p, v);
#else
    atomicAdd(p, v);
#endif
}

__global__ __launch_bounds__(256) void edge_kernel(
        const int* __restrict__ edge,
        const float* __restrict__ sp,
        const float* __restrict__ qp,
        float* __restrict__ acc) {
    int e = blockIdx.x * 256 + threadIdx.x;
    if (e >= N_EDGES) return;
    int q = edge[e];
    int s = edge[N_EDGES + e];
    float sx = sp[3 * s + 0], sy = sp[3 * s + 1], sz = sp[3 * s + 2];
    float qx = qp[3 * q + 0], qy = qp[3 * q + 1], qz = qp[3 * q + 2];
    float dx = sx - qx, dy = sy - qy, dz = sz - qz;
    float d2 = dx * dx + dy * dy + dz * dz;
    float dist = sqrtf(d2);
    atomAddF(acc + 0 * Q_NODES + q, 1.0f);
    atomAddF(acc + 1 * Q_NODES + q, dist);
    atomAddF(acc + 2 * Q_NODES + q, d2);
    atomAddF(acc + 3 * Q_NODES + q, sx);
    atomAddF(acc + 4 * Q_NODES + q, sy);
    atomAddF(acc + 5 * Q_NODES + q, sz);
    atomAddF(acc + 6 * Q_NODES + q, sx * sx);
    atomAddF(acc + 7 * Q_NODES + q, sx * sy);
    atomAddF(acc + 8 * Q_NODES + q, sx * sz);
    atomAddF(acc + 9 * Q_NODES + q, sy * sy);
    atomAddF(acc + 10 * Q_NODES + q, sy * sz);
    atomAddF(acc + 11 * Q_NODES + q, sz * sz);
}

__global__ __launch_bounds__(256) void finalize_kernel(
        const float* __restrict__ acc,
        const float* __restrict__ qp,
        float* __restrict__ feats,
        double* __restrict__ stats) {
    int q = blockIdx.x * 256 + threadIdx.x;
    float f[9];
#pragma unroll
    for (int k = 0; k < 9; ++k) f[k] = 0.0f;

    if (q < Q_NODES) {
        float n = acc[q];
        if (n > 0.0f) {
            float inv = 1.0f / n;
            float Davg = acc[1 * Q_NODES + q] * inv;
            float Dvar = fmaxf(acc[2 * Q_NODES + q] * inv - Davg * Davg, 0.0f);
            float cx = acc[3 * Q_NODES + q] * inv;
            float cy = acc[4 * Q_NODES + q] * inv;
            float cz = acc[5 * Q_NODES + q] * inv;
            float qx = qp[3 * q + 0], qy = qp[3 * q + 1], qz = qp[3 * q + 2];
            // cov = E[xx^T] - c c^T
            float a00 = fmaxf(acc[6 * Q_NODES + q] * inv - cx * cx, 0.0f);
            float a01 = acc[7 * Q_NODES + q] * inv - cx * cy;
            float a02 = acc[8 * Q_NODES + q] * inv - cx * cz;
            float a11 = fmaxf(acc[9 * Q_NODES + q] * inv - cy * cy, 0.0f);
            float a12 = acc[10 * Q_NODES + q] * inv - cy * cz;
            float a22 = fmaxf(acc[11 * Q_NODES + q] * inv - cz * cz, 0.0f);

            // 3x3 symmetric eigenvalues (Smith's method), descending e1>=e2>=e3
            float p1 = a01 * a01 + a02 * a02 + a12 * a12;
            float qm = (a00 + a11 + a22) * (1.0f / 3.0f);
            float b00 = a00 - qm, b11 = a11 - qm, b22 = a22 - qm;
            float p2 = b00 * b00 + b11 * b11 + b22 * b22 + 2.0f * p1;
            float e1, e2, e3;
            if (p2 <= 1e-24f) {
                e1 = qm; e2 = qm; e3 = qm;
            } else {
                float p = sqrtf(p2 * (1.0f / 6.0f));
                float invp = 1.0f / p;
                float c00 = b00 * invp, c11 = b11 * invp, c22 = b22 * invp;
                float c01 = a01 * invp, c02 = a02 * invp, c12 = a12 * invp;
                float detB = c00 * (c11 * c22 - c12 * c12)
                           - c01 * (c01 * c22 - c12 * c02)
                           + c02 * (c01 * c12 - c11 * c02);
                float r = 0.5f * detB;
                r = fminf(fmaxf(r, -1.0f), 1.0f);
                float phi = acosf(r) * (1.0f / 3.0f);
                e1 = qm + 2.0f * p * cosf(phi);
                e3 = qm + 2.0f * p * cosf(phi + 2.0943951023931953f); // +2pi/3
                e2 = 3.0f * qm - e1 - e3;
            }
            f[0] = n; f[1] = Davg; f[2] = Dvar;
            f[3] = cx - qx; f[4] = cy - qy; f[5] = cz - qz;
            f[6] = e1; f[7] = e2; f[8] = e3;
        }
#pragma unroll
        for (int k = 0; k < 9; ++k) feats[k * Q_NODES + q] = f[k];
    }

    // wave-level reduction of sum / sumsq, one double atomic per wave per stat
    int lane = threadIdx.x & 63;
#pragma unroll
    for (int k = 0; k < 9; ++k) {
        float s1 = f[k];
        float s2 = f[k] * f[k];
        for (int off = 32; off > 0; off >>= 1) {
            s1 += __shfl_down(s1, off);
            s2 += __shfl_down(s2, off);
        }
        if (lane == 0) {
            atomicAdd(&stats[k], (double)s1);
            atomicAdd(&stats[9 + k], (double)s2);
        }
    }
}

__global__ void stats_kernel(const double* __restrict__ stats,
                             float* __restrict__ norm) {
    int k = threadIdx.x;
    if (k < 9) {
        double S = stats[k], S2 = stats[9 + k];
        double mean = S / (double)Q_NODES;
        double var = (S2 - S * S / (double)Q_NODES) / (double)(Q_NODES - 1);
        if (var < 0.0) var = 0.0;
        double sd = sqrt(var);
        if (sd < 1e-6) sd = 1.0;
        norm[k] = (float)mean;
        norm[9 + k] = (float)(1.0 / sd);
    }
}

__global__ __launch_bounds__(256) void mlp_kernel(
        const float* __restrict__ feats,
        const float* __restrict__ norm,
        const float* __restrict__ W1, const float* __restrict__ b1,
        const float* __restrict__ W2, const float* __restrict__ b2,
        float* __restrict__ out) {
    __shared__ float sm[576 + 64 + 8192 + 128 + 18];
    float* sW1 = sm;                 // [64][9]
    float* sB1 = sm + 576;           // [64]
    float* sW2 = sm + 640;           // [128][64]
    float* sB2 = sm + 8832;          // [128]
    float* sNorm = sm + 8960;        // [18]

    for (int i = threadIdx.x; i < 576; i += 256) sW1[i] = W1[i];
    if (threadIdx.x < 64) sB1[threadIdx.x] = b1[threadIdx.x];
    for (int i = threadIdx.x; i < 8192; i += 256) sW2[i] = W2[i];
    if (threadIdx.x < 128) sB2[threadIdx.x] = b2[threadIdx.x];
    if (threadIdx.x < 18) sNorm[threadIdx.x] = norm[threadIdx.x];
    __syncthreads();

    int q = blockIdx.x * 256 + threadIdx.x;
    bool valid = q < Q_NODES;
    int qq = valid ? q : 0;

    float f[9];
#pragma unroll
    for (int k = 0; k < 9; ++k)
        f[k] = (feats[k * Q_NODES + qq] - sNorm[k]) * sNorm[9 + k];

    float h[64];
#pragma unroll
    for (int j = 0; j < 64; ++j) {
        float a = sB1[j];
#pragma unroll
        for (int k = 0; k < 9; ++k) a = fmaf(f[k], sW1[j * 9 + k], a);
        h[j] = fmaxf(a, 0.0f);
    }

    if (!valid) return;
    float* op = out + (size_t)q * 128;
#pragma unroll 1
    for (int o = 0; o < 128; o += 4) {
        float a0 = sB2[o + 0], a1 = sB2[o + 1], a2 = sB2[o + 2], a3 = sB2[o + 3];
#pragma unroll
        for (int j = 0; j < 64; j += 4) {
            float4 w0 = *(const float4*)&sW2[(o + 0) * 64 + j];
            float4 w1 = *(const float4*)&sW2[(o + 1) * 64 + j];
            float4 w2 = *(const float4*)&sW2[(o + 2) * 64 + j];
            float4 w3 = *(const float4*)&sW2[(o + 3) * 64 + j];
            float h0 = h[j], h1 = h[j + 1], h2 = h[j + 2], h3 = h[j + 3];
            a0 = fmaf(h0, w0.x, a0); a0 = fmaf(h1, w0.y, a0); a0 = fmaf(h2, w0.z, a0); a0 = fmaf(h3, w0.w, a0);
            a1 = fmaf(h0, w1.x, a1); a1 = fmaf(h1, w1.y, a1); a1 = fmaf(h2, w1.z, a1); a1 = fmaf(h3, w1.w, a1);
            a2 = fmaf(h0, w2.x, a2); a2 = fmaf(h1, w2.y, a2); a2 = fmaf(h2, w2.z, a2); a2 = fmaf(h3, w2.w, a2);
            a3 = fmaf(h0, w3.x, a3); a3 = fmaf(h1, w3.y, a3); a3 = fmaf(h2, w3.z, a3); a3 = fmaf(h3, w3.w, a3);
        }
        float4 v = make_float4(a0, a1, a2, a3);
        *(float4*)(op + o) = v;
    }
}

extern "C" void kernel_launch(void* const* d_in, const int* in_sizes, int n_in,
                              void* d_out, int out_size, void* d_ws, size_t ws_size,
                              hipStream_t stream) {
    const float* sp   = (const float*)d_in[0];
    const float* qp   = (const float*)d_in[1];
    const int*   edge = (const int*)d_in[2];
    const float* W1   = (const float*)d_in[3];
    const float* b1   = (const float*)d_in[4];
    const float* W2   = (const float*)d_in[5];
    const float* b2   = (const float*)d_in[6];
    float* out = (float*)d_out;

    char* ws = (char*)d_ws;
    float*  acc   = (float*)(ws + ACC_OFF);
    double* stats = (double*)(ws + STATS_OFF);
    float*  norm  = (float*)(ws + NORM_OFF);
    float*  feats = (float*)(ws + FEATS_OFF);

    hipMemsetAsync(ws, 0, ZERO_BYTES, stream);

    edge_kernel<<<N_EDGES / 256, 256, 0, stream>>>(edge, sp, qp, acc);
    finalize_kernel<<<(Q_NODES + 255) / 256, 256, 0, stream>>>(acc, qp, feats, stats);
    stats_kernel<<<1, 64, 0, stream>>>(stats, norm);
    mlp_kernel<<<(Q_NODES + 255) / 256, 256, 0, stream>>>(feats, norm, W1, b1, W2, b2, out);
}

// Round 2
// 687.738 us; speedup vs baseline: 3.1634x; 3.1634x over previous
//
#include <hip/hip_runtime.h>
#include <math.h>

#define Q_NODES 100000
#define S_NODES 100000
#define N_EDGES 3200000
#define HIDDEN 64
#define OUT_DIM 128
#define CAP 96          // max neighbors per query slot array (Poisson(32) tail @96 ~ 1e-18)

// ---------- FAST-PATH workspace layout (bytes) ----------
//   [0,        400000)   cursor : Q ints (neighbor counts, doubles as fetch-add cursor)
//   [400000,   400144)   stats  : 18 doubles (sum[9], sumsq[9])
//   [400160,   400240)   norm   : 18 floats (mean[9], inv_std[9])
//   [400256,  4000256)   feats  : 9 * Q floats (SoA)
//   [4000256, 42400256)  slots  : Q * CAP ints (source index per neighbor)
#define F_CURSOR_OFF 0
#define F_STATS_OFF  400000
#define F_NORM_OFF   400160
#define F_FEATS_OFF  400256
#define F_SLOTS_OFF  4000256
#define F_ZERO_BYTES 400160        // cursor + stats
#define F_WS_NEED    42400256ull

// ---------- FALLBACK workspace layout (round-1 algorithm) ----------
#define B_ACC_OFF    0
#define B_STATS_OFF  4800000
#define B_NORM_OFF   4800144
#define B_FEATS_OFF  4800224
#define B_ZERO_BYTES 4800144
#define B_WS_NEED    8400224ull

__device__ __forceinline__ void atomAddF(float* p, float v) {
#if defined(__gfx950__) || defined(__gfx942__) || defined(__gfx90a__)
    unsafeAtomicAdd(p, v);
#else
    atomicAdd(p, v);
#endif
}

// ============================================================================
// Shared device helpers
// ============================================================================

// 3x3 symmetric eigenvalues (Smith's trig method), descending e1>=e2>=e3.
__device__ __forceinline__ void eig3_sym(
        float a00, float a01, float a02, float a11, float a12, float a22,
        float& e1, float& e2, float& e3) {
    float p1 = a01 * a01 + a02 * a02 + a12 * a12;
    float qm = (a00 + a11 + a22) * (1.0f / 3.0f);
    float b00 = a00 - qm, b11 = a11 - qm, b22 = a22 - qm;
    float p2 = b00 * b00 + b11 * b11 + b22 * b22 + 2.0f * p1;
    if (p2 <= 1e-24f) {
        e1 = qm; e2 = qm; e3 = qm;
    } else {
        float p = sqrtf(p2 * (1.0f / 6.0f));
        float invp = 1.0f / p;
        float c00 = b00 * invp, c11 = b11 * invp, c22 = b22 * invp;
        float c01 = a01 * invp, c02 = a02 * invp, c12 = a12 * invp;
        float detB = c00 * (c11 * c22 - c12 * c12)
                   - c01 * (c01 * c22 - c12 * c02)
                   + c02 * (c01 * c12 - c11 * c02);
        float r = 0.5f * detB;
        r = fminf(fmaxf(r, -1.0f), 1.0f);
        float phi = acosf(r) * (1.0f / 3.0f);
        e1 = qm + 2.0f * p * cosf(phi);
        e3 = qm + 2.0f * p * cosf(phi + 2.0943951023931953f); // +2pi/3
        e2 = 3.0f * qm - e1 - e3;
    }
}

// Turn raw sums into the 9 features for query q. sums: n,sumd,sumd2,sx,sy,sz,xx,xy,xz,yy,yz,zz
__device__ __forceinline__ void sums_to_feats(
        const float* s, float qx, float qy, float qz, float* f) {
    float n = s[0];
#pragma unroll
    for (int k = 0; k < 9; ++k) f[k] = 0.0f;
    if (n > 0.0f) {
        float inv = 1.0f / n;
        float Davg = s[1] * inv;
        float Dvar = fmaxf(s[2] * inv - Davg * Davg, 0.0f);
        float cx = s[3] * inv, cy = s[4] * inv, cz = s[5] * inv;
        float a00 = fmaxf(s[6] * inv - cx * cx, 0.0f);
        float a01 = s[7] * inv - cx * cy;
        float a02 = s[8] * inv - cx * cz;
        float a11 = fmaxf(s[9] * inv - cy * cy, 0.0f);
        float a12 = s[10] * inv - cy * cz;
        float a22 = fmaxf(s[11] * inv - cz * cz, 0.0f);
        float e1, e2, e3;
        eig3_sym(a00, a01, a02, a11, a12, a22, e1, e2, e3);
        f[0] = n; f[1] = Davg; f[2] = Dvar;
        f[3] = cx - qx; f[4] = cy - qy; f[5] = cz - qz;
        f[6] = e1; f[7] = e2; f[8] = e3;
    }
}

// ============================================================================
// FAST PATH
// ============================================================================

__global__ __launch_bounds__(256) void scatter_kernel(
        const int* __restrict__ edge,
        int* __restrict__ cursor,
        int* __restrict__ slots) {
    int e = blockIdx.x * 256 + threadIdx.x;
    if (e >= N_EDGES) return;
    int q = edge[e];
    int s = edge[N_EDGES + e];
    int pos = atomicAdd(&cursor[q], 1);
    if (pos < CAP) slots[q * CAP + pos] = s;
}

__global__ __launch_bounds__(256) void gather_finalize_kernel(
        const int* __restrict__ cursor,
        const int* __restrict__ slots,
        const float* __restrict__ sp,
        const float* __restrict__ qp,
        float* __restrict__ feats) {
    int wave = threadIdx.x >> 6;               // 4 waves per block
    int lane = threadIdx.x & 63;
    int q = blockIdx.x * 4 + wave;
    if (q >= Q_NODES) return;

    int cnt = cursor[q];
    if (cnt > CAP) cnt = CAP;                  // memory-safety guard (never taken in practice)
    float qx = qp[3 * q + 0], qy = qp[3 * q + 1], qz = qp[3 * q + 2];

    float s[12];
#pragma unroll
    for (int k = 0; k < 12; ++k) s[k] = 0.0f;

    for (int i = lane; i < cnt; i += 64) {
        int si = slots[q * CAP + i];
        float sx = sp[3 * si + 0], sy = sp[3 * si + 1], sz = sp[3 * si + 2];
        float dx = sx - qx, dy = sy - qy, dz = sz - qz;
        float d2 = dx * dx + dy * dy + dz * dz;
        s[0] += 1.0f;
        s[1] += sqrtf(d2);
        s[2] += d2;
        s[3] += sx; s[4] += sy; s[5] += sz;
        s[6] += sx * sx; s[7] += sx * sy; s[8] += sx * sz;
        s[9] += sy * sy; s[10] += sy * sz; s[11] += sz * sz;
    }
#pragma unroll
    for (int off = 32; off > 0; off >>= 1) {
#pragma unroll
        for (int k = 0; k < 12; ++k) s[k] += __shfl_xor(s[k], off);
    }

    if (lane == 0) {
        float f[9];
        sums_to_feats(s, qx, qy, qz, f);
#pragma unroll
        for (int k = 0; k < 9; ++k) feats[k * Q_NODES + q] = f[k];
    }
}

__global__ __launch_bounds__(256) void feat_stats_kernel(
        const float* __restrict__ feats,
        double* __restrict__ stats) {
    int q = blockIdx.x * 256 + threadIdx.x;
    float f[9];
#pragma unroll
    for (int k = 0; k < 9; ++k) f[k] = (q < Q_NODES) ? feats[k * Q_NODES + q] : 0.0f;

    int lane = threadIdx.x & 63;
#pragma unroll
    for (int k = 0; k < 9; ++k) {
        float s1 = f[k];
        float s2 = f[k] * f[k];
#pragma unroll
        for (int off = 32; off > 0; off >>= 1) {
            s1 += __shfl_down(s1, off);
            s2 += __shfl_down(s2, off);
        }
        if (lane == 0) {
            atomicAdd(&stats[k], (double)s1);
            atomicAdd(&stats[9 + k], (double)s2);
        }
    }
}

// ============================================================================
// FALLBACK PATH (round-1 algorithm, used only if ws_size too small)
// ============================================================================

__global__ __launch_bounds__(256) void edge_kernel(
        const int* __restrict__ edge,
        const float* __restrict__ sp,
        const float* __restrict__ qp,
        float* __restrict__ acc) {
    int e = blockIdx.x * 256 + threadIdx.x;
    if (e >= N_EDGES) return;
    int q = edge[e];
    int s = edge[N_EDGES + e];
    float sx = sp[3 * s + 0], sy = sp[3 * s + 1], sz = sp[3 * s + 2];
    float qx = qp[3 * q + 0], qy = qp[3 * q + 1], qz = qp[3 * q + 2];
    float dx = sx - qx, dy = sy - qy, dz = sz - qz;
    float d2 = dx * dx + dy * dy + dz * dz;
    atomAddF(acc + 0 * Q_NODES + q, 1.0f);
    atomAddF(acc + 1 * Q_NODES + q, sqrtf(d2));
    atomAddF(acc + 2 * Q_NODES + q, d2);
    atomAddF(acc + 3 * Q_NODES + q, sx);
    atomAddF(acc + 4 * Q_NODES + q, sy);
    atomAddF(acc + 5 * Q_NODES + q, sz);
    atomAddF(acc + 6 * Q_NODES + q, sx * sx);
    atomAddF(acc + 7 * Q_NODES + q, sx * sy);
    atomAddF(acc + 8 * Q_NODES + q, sx * sz);
    atomAddF(acc + 9 * Q_NODES + q, sy * sy);
    atomAddF(acc + 10 * Q_NODES + q, sy * sz);
    atomAddF(acc + 11 * Q_NODES + q, sz * sz);
}

__global__ __launch_bounds__(256) void finalize_kernel(
        const float* __restrict__ acc,
        const float* __restrict__ qp,
        float* __restrict__ feats,
        double* __restrict__ stats) {
    int q = blockIdx.x * 256 + threadIdx.x;
    float f[9];
#pragma unroll
    for (int k = 0; k < 9; ++k) f[k] = 0.0f;
    if (q < Q_NODES) {
        float s[12];
#pragma unroll
        for (int k = 0; k < 12; ++k) s[k] = acc[k * Q_NODES + q];
        float qx = qp[3 * q + 0], qy = qp[3 * q + 1], qz = qp[3 * q + 2];
        sums_to_feats(s, qx, qy, qz, f);
#pragma unroll
        for (int k = 0; k < 9; ++k) feats[k * Q_NODES + q] = f[k];
    }
    int lane = threadIdx.x & 63;
#pragma unroll
    for (int k = 0; k < 9; ++k) {
        float s1 = f[k];
        float s2 = f[k] * f[k];
#pragma unroll
        for (int off = 32; off > 0; off >>= 1) {
            s1 += __shfl_down(s1, off);
            s2 += __shfl_down(s2, off);
        }
        if (lane == 0) {
            atomicAdd(&stats[k], (double)s1);
            atomicAdd(&stats[9 + k], (double)s2);
        }
    }
}

// ============================================================================
// Shared tail kernels
// ============================================================================

__global__ void stats_kernel(const double* __restrict__ stats,
                             float* __restrict__ norm) {
    int k = threadIdx.x;
    if (k < 9) {
        double S = stats[k], S2 = stats[9 + k];
        double mean = S / (double)Q_NODES;
        double var = (S2 - S * S / (double)Q_NODES) / (double)(Q_NODES - 1);
        if (var < 0.0) var = 0.0;
        double sd = sqrt(var);
        if (sd < 1e-6) sd = 1.0;
        norm[k] = (float)mean;
        norm[9 + k] = (float)(1.0 / sd);
    }
}

__global__ __launch_bounds__(256) void mlp_kernel(
        const float* __restrict__ feats,
        const float* __restrict__ norm,
        const float* __restrict__ W1, const float* __restrict__ b1,
        const float* __restrict__ W2, const float* __restrict__ b2,
        float* __restrict__ out) {
    __shared__ float sm[576 + 64 + 8192 + 128 + 18];
    float* sW1 = sm;                 // [64][9]
    float* sB1 = sm + 576;           // [64]
    float* sW2 = sm + 640;           // [128][64]
    float* sB2 = sm + 8832;          // [128]
    float* sNorm = sm + 8960;        // [18]

    for (int i = threadIdx.x; i < 576; i += 256) sW1[i] = W1[i];
    if (threadIdx.x < 64) sB1[threadIdx.x] = b1[threadIdx.x];
    for (int i = threadIdx.x; i < 8192; i += 256) sW2[i] = W2[i];
    if (threadIdx.x < 128) sB2[threadIdx.x] = b2[threadIdx.x];
    if (threadIdx.x < 18) sNorm[threadIdx.x] = norm[threadIdx.x];
    __syncthreads();

    int q = blockIdx.x * 256 + threadIdx.x;
    bool valid = q < Q_NODES;
    int qq = valid ? q : 0;

    float f[9];
#pragma unroll
    for (int k = 0; k < 9; ++k)
        f[k] = (feats[k * Q_NODES + qq] - sNorm[k]) * sNorm[9 + k];

    float h[64];
#pragma unroll
    for (int j = 0; j < 64; ++j) {
        float a = sB1[j];
#pragma unroll
        for (int k = 0; k < 9; ++k) a = fmaf(f[k], sW1[j * 9 + k], a);
        h[j] = fmaxf(a, 0.0f);
    }

    if (!valid) return;
    float* op = out + (size_t)q * 128;
#pragma unroll 1
    for (int o = 0; o < 128; o += 4) {
        float a0 = sB2[o + 0], a1 = sB2[o + 1], a2 = sB2[o + 2], a3 = sB2[o + 3];
#pragma unroll
        for (int j = 0; j < 64; j += 4) {
            float4 w0 = *(const float4*)&sW2[(o + 0) * 64 + j];
            float4 w1 = *(const float4*)&sW2[(o + 1) * 64 + j];
            float4 w2 = *(const float4*)&sW2[(o + 2) * 64 + j];
            float4 w3 = *(const float4*)&sW2[(o + 3) * 64 + j];
            float h0 = h[j], h1 = h[j + 1], h2 = h[j + 2], h3 = h[j + 3];
            a0 = fmaf(h0, w0.x, a0); a0 = fmaf(h1, w0.y, a0); a0 = fmaf(h2, w0.z, a0); a0 = fmaf(h3, w0.w, a0);
            a1 = fmaf(h0, w1.x, a1); a1 = fmaf(h1, w1.y, a1); a1 = fmaf(h2, w1.z, a1); a1 = fmaf(h3, w1.w, a1);
            a2 = fmaf(h0, w2.x, a2); a2 = fmaf(h1, w2.y, a2); a2 = fmaf(h2, w2.z, a2); a2 = fmaf(h3, w2.w, a2);
            a3 = fmaf(h0, w3.x, a3); a3 = fmaf(h1, w3.y, a3); a3 = fmaf(h2, w3.z, a3); a3 = fmaf(h3, w3.w, a3);
        }
        float4 v = make_float4(a0, a1, a2, a3);
        *(float4*)(op + o) = v;
    }
}

// ============================================================================

extern "C" void kernel_launch(void* const* d_in, const int* in_sizes, int n_in,
                              void* d_out, int out_size, void* d_ws, size_t ws_size,
                              hipStream_t stream) {
    const float* sp   = (const float*)d_in[0];
    const float* qp   = (const float*)d_in[1];
    const int*   edge = (const int*)d_in[2];
    const float* W1   = (const float*)d_in[3];
    const float* b1   = (const float*)d_in[4];
    const float* W2   = (const float*)d_in[5];
    const float* b2   = (const float*)d_in[6];
    float* out = (float*)d_out;
    char* ws = (char*)d_ws;

    if (ws_size >= F_WS_NEED) {
        int*    cursor = (int*)(ws + F_CURSOR_OFF);
        double* stats  = (double*)(ws + F_STATS_OFF);
        float*  norm   = (float*)(ws + F_NORM_OFF);
        float*  feats  = (float*)(ws + F_FEATS_OFF);
        int*    slots  = (int*)(ws + F_SLOTS_OFF);

        hipMemsetAsync(ws, 0, F_ZERO_BYTES, stream);
        scatter_kernel<<<N_EDGES / 256, 256, 0, stream>>>(edge, cursor, slots);
        gather_finalize_kernel<<<Q_NODES / 4, 256, 0, stream>>>(cursor, slots, sp, qp, feats);
        feat_stats_kernel<<<(Q_NODES + 255) / 256, 256, 0, stream>>>(feats, stats);
        stats_kernel<<<1, 64, 0, stream>>>(stats, norm);
        mlp_kernel<<<(Q_NODES + 255) / 256, 256, 0, stream>>>(feats, norm, W1, b1, W2, b2, out);
    } else {
        float*  acc   = (float*)(ws + B_ACC_OFF);
        double* stats = (double*)(ws + B_STATS_OFF);
        float*  norm  = (float*)(ws + B_NORM_OFF);
        float*  feats = (float*)(ws + B_FEATS_OFF);

        hipMemsetAsync(ws, 0, B_ZERO_BYTES, stream);
        edge_kernel<<<N_EDGES / 256, 256, 0, stream>>>(edge, sp, qp, acc);
        finalize_kernel<<<(Q_NODES + 255) / 256, 256, 0, stream>>>(acc, qp, feats, stats);
        stats_kernel<<<1, 64, 0, stream>>>(stats, norm);
        mlp_kernel<<<(Q_NODES + 255) / 256, 256, 0, stream>>>(feats, norm, W1, b1, W2, b2, out);
    }
}

// Round 3
// 661.281 us; speedup vs baseline: 3.2900x; 1.0400x over previous
//
#include <hip/hip_runtime.h>
#include <math.h>

#define Q_NODES 100000
#define S_NODES 100000
#define N_EDGES 3200000
#define HIDDEN 64
#define OUT_DIM 128

// ---------- bucket partition parameters ----------
#define QPB   128                    // queries per bucket (bucket = q >> 7)
#define NB    782                    // ceil(Q_NODES / QPB)
#define CAPB  4608                   // bucket capacity: mean 4096, +8 sigma
#define TILE  4096                   // edges per partition block
#define EPT   16                     // TILE / 256

// ---------- FAST-PATH workspace layout (bytes) ----------
//   [0,       3128)      cursor : NB ints (per-bucket fill count)
//   [3200,    3344)      stats  : 18 doubles (sum[9], sumsq[9])
//   [3360,    3440)      norm   : 18 floats (mean[9], inv_std[9])
//   [3456,    3603456)   feats  : 9 * Q floats (SoA)
//   [3603456, 18017280)  slots  : NB * CAPB uint32 packed records (qlow<<17 | s)
#define F_CURSOR_OFF 0
#define F_STATS_OFF  3200
#define F_NORM_OFF   3360
#define F_FEATS_OFF  3456
#define F_SLOTS_OFF  3603456
#define F_ZERO_BYTES 3344            // cursor + stats
#define F_WS_NEED    18017280ull

// ---------- FALLBACK workspace layout (round-1 algorithm) ----------
#define B_ACC_OFF    0
#define B_STATS_OFF  4800000
#define B_NORM_OFF   4800144
#define B_FEATS_OFF  4800224
#define B_ZERO_BYTES 4800144
#define B_WS_NEED    8400224ull

__device__ __forceinline__ void atomAddF(float* p, float v) {
#if defined(__gfx950__) || defined(__gfx942__) || defined(__gfx90a__)
    unsafeAtomicAdd(p, v);
#else
    atomicAdd(p, v);
#endif
}

// ============================================================================
// Shared device helpers
// ============================================================================

// 3x3 symmetric eigenvalues (Smith's trig method), descending e1>=e2>=e3.
__device__ __forceinline__ void eig3_sym(
        float a00, float a01, float a02, float a11, float a12, float a22,
        float& e1, float& e2, float& e3) {
    float p1 = a01 * a01 + a02 * a02 + a12 * a12;
    float qm = (a00 + a11 + a22) * (1.0f / 3.0f);
    float b00 = a00 - qm, b11 = a11 - qm, b22 = a22 - qm;
    float p2 = b00 * b00 + b11 * b11 + b22 * b22 + 2.0f * p1;
    if (p2 <= 1e-24f) {
        e1 = qm; e2 = qm; e3 = qm;
    } else {
        float p = sqrtf(p2 * (1.0f / 6.0f));
        float invp = 1.0f / p;
        float c00 = b00 * invp, c11 = b11 * invp, c22 = b22 * invp;
        float c01 = a01 * invp, c02 = a02 * invp, c12 = a12 * invp;
        float detB = c00 * (c11 * c22 - c12 * c12)
                   - c01 * (c01 * c22 - c12 * c02)
                   + c02 * (c01 * c12 - c11 * c02);
        float r = 0.5f * detB;
        r = fminf(fmaxf(r, -1.0f), 1.0f);
        float phi = acosf(r) * (1.0f / 3.0f);
        e1 = qm + 2.0f * p * cosf(phi);
        e3 = qm + 2.0f * p * cosf(phi + 2.0943951023931953f); // +2pi/3
        e2 = 3.0f * qm - e1 - e3;
    }
}

// sums: n,sumd,sumd2,sx,sy,sz,xx,xy,xz,yy,yz,zz -> 9 features
__device__ __forceinline__ void sums_to_feats(
        const float* s, float qx, float qy, float qz, float* f) {
    float n = s[0];
#pragma unroll
    for (int k = 0; k < 9; ++k) f[k] = 0.0f;
    if (n > 0.0f) {
        float inv = 1.0f / n;
        float Davg = s[1] * inv;
        float Dvar = fmaxf(s[2] * inv - Davg * Davg, 0.0f);
        float cx = s[3] * inv, cy = s[4] * inv, cz = s[5] * inv;
        float a00 = fmaxf(s[6] * inv - cx * cx, 0.0f);
        float a01 = s[7] * inv - cx * cy;
        float a02 = s[8] * inv - cx * cz;
        float a11 = fmaxf(s[9] * inv - cy * cy, 0.0f);
        float a12 = s[10] * inv - cy * cz;
        float a22 = fmaxf(s[11] * inv - cz * cz, 0.0f);
        float e1, e2, e3;
        eig3_sym(a00, a01, a02, a11, a12, a22, e1, e2, e3);
        f[0] = n; f[1] = Davg; f[2] = Dvar;
        f[3] = cx - qx; f[4] = cy - qy; f[5] = cz - qz;
        f[6] = e1; f[7] = e2; f[8] = e3;
    }
}

// ============================================================================
// FAST PATH: LDS-binned partition + per-bucket LDS accumulate
// ============================================================================

__global__ __launch_bounds__(256) void partition_kernel(
        const int* __restrict__ edge,
        int* __restrict__ cursor,
        unsigned int* __restrict__ slots) {
    __shared__ unsigned int   s_rec[TILE];      // 16 KB
    __shared__ unsigned short s_bkt[TILE];      // 8 KB
    __shared__ int s_hist[NB];
    __shared__ int s_pref[NB];
    __shared__ int s_rank[NB];
    __shared__ int s_base[NB];
    __shared__ int s_scan[256];

    int tid = threadIdx.x;
    int tileStart = blockIdx.x * TILE;
    int tileCount = N_EDGES - tileStart;
    if (tileCount > TILE) tileCount = TILE;

    for (int b = tid; b < NB; b += 256) { s_hist[b] = 0; s_rank[b] = 0; }
    __syncthreads();

    int q[EPT], s[EPT];
    bool v[EPT];
#pragma unroll
    for (int j = 0; j < EPT; ++j) {
        int e = tileStart + tid + j * 256;
        v[j] = e < N_EDGES;
        int ec = v[j] ? e : 0;
        q[j] = edge[ec];
        s[j] = edge[N_EDGES + ec];
        if (v[j]) atomicAdd(&s_hist[q[j] >> 7], 1);
    }
    __syncthreads();

    // exclusive prefix of s_hist -> s_pref (256 threads x 4 entries, padded)
    int local[4];
    int tsum = 0;
#pragma unroll
    for (int j = 0; j < 4; ++j) {
        int idx = 4 * tid + j;
        local[j] = (idx < NB) ? s_hist[idx] : 0;
        tsum += local[j];
    }
    s_scan[tid] = tsum;
    __syncthreads();
    for (int off = 1; off < 256; off <<= 1) {
        int vv = (tid >= off) ? s_scan[tid - off] : 0;
        __syncthreads();
        s_scan[tid] += vv;
        __syncthreads();
    }
    int run = s_scan[tid] - tsum;
#pragma unroll
    for (int j = 0; j < 4; ++j) {
        int idx = 4 * tid + j;
        if (idx < NB) s_pref[idx] = run;
        run += local[j];
    }
    // reserve global space per bucket (one atomic per non-empty bucket)
    for (int b = tid; b < NB; b += 256) {
        int c = s_hist[b];
        s_base[b] = c ? atomicAdd(&cursor[b], c) : 0;
    }
    __syncthreads();

    // scatter into bucket-sorted LDS stage
#pragma unroll
    for (int j = 0; j < EPT; ++j) {
        if (v[j]) {
            int bkt = q[j] >> 7;
            int r = atomicAdd(&s_rank[bkt], 1);
            int idx = s_pref[bkt] + r;
            s_rec[idx] = ((unsigned)(q[j] & (QPB - 1)) << 17) | (unsigned)s[j];
            s_bkt[idx] = (unsigned short)bkt;
        }
    }
    __syncthreads();

    // bucket-contiguous write-out (runs of same bucket are consecutive)
    for (int i = tid; i < tileCount; i += 256) {
        int bkt = s_bkt[i];
        int ofs = s_base[bkt] + (i - s_pref[bkt]);
        if (ofs < CAPB) slots[bkt * CAPB + ofs] = s_rec[i];
    }
}

__global__ __launch_bounds__(256) void bucket_kernel(
        const int* __restrict__ cursor,
        const unsigned int* __restrict__ slots,
        const float* __restrict__ sp,
        const float* __restrict__ qp,
        float* __restrict__ feats,
        double* __restrict__ stats) {
    __shared__ float facc[QPB * 13];   // stride 13: conflict-spread, 6.5 KB
    __shared__ float qtile[QPB * 3];

    int tid = threadIdx.x;
    int b = blockIdx.x;

    for (int i = tid; i < QPB * 13; i += 256) facc[i] = 0.0f;
    for (int i = tid; i < QPB * 3; i += 256) {
        int g = b * QPB * 3 + i;
        qtile[i] = (g < Q_NODES * 3) ? qp[g] : 0.0f;
    }
    __syncthreads();

    int cnt = cursor[b];
    if (cnt > CAPB) cnt = CAPB;

    for (int i = tid; i < cnt; i += 256) {
        unsigned rec = slots[b * CAPB + i];
        int qlow = rec >> 17;
        int si = rec & 0x1FFFF;
        float sx = sp[3 * si + 0], sy = sp[3 * si + 1], sz = sp[3 * si + 2];
        float qx = qtile[3 * qlow + 0], qy = qtile[3 * qlow + 1], qz = qtile[3 * qlow + 2];
        float dx = sx - qx, dy = sy - qy, dz = sz - qz;
        float d2 = dx * dx + dy * dy + dz * dz;
        float* fa = facc + qlow * 13;
        atomicAdd(fa + 0, 1.0f);
        atomicAdd(fa + 1, sqrtf(d2));
        atomicAdd(fa + 2, d2);
        atomicAdd(fa + 3, sx);
        atomicAdd(fa + 4, sy);
        atomicAdd(fa + 5, sz);
        atomicAdd(fa + 6, sx * sx);
        atomicAdd(fa + 7, sx * sy);
        atomicAdd(fa + 8, sx * sz);
        atomicAdd(fa + 9, sy * sy);
        atomicAdd(fa + 10, sy * sz);
        atomicAdd(fa + 11, sz * sz);
    }
    __syncthreads();

    // finalize: threads 0..127 each own one query
    float f[9];
#pragma unroll
    for (int k = 0; k < 9; ++k) f[k] = 0.0f;
    int q = b * QPB + tid;
    if (tid < QPB && q < Q_NODES) {
        float sums[12];
#pragma unroll
        for (int k = 0; k < 12; ++k) sums[k] = facc[tid * 13 + k];
        sums_to_feats(sums, qtile[3 * tid + 0], qtile[3 * tid + 1], qtile[3 * tid + 2], f);
#pragma unroll
        for (int k = 0; k < 9; ++k) feats[k * Q_NODES + q] = f[k];  // coalesced per k
    }

    // dataset-wide stats: wave reduce, lane0 double-atomic (invalid threads add 0)
    int lane = tid & 63;
#pragma unroll
    for (int k = 0; k < 9; ++k) {
        float s1 = f[k];
        float s2 = f[k] * f[k];
#pragma unroll
        for (int off = 32; off > 0; off >>= 1) {
            s1 += __shfl_down(s1, off);
            s2 += __shfl_down(s2, off);
        }
        if (lane == 0) {
            atomicAdd(&stats[k], (double)s1);
            atomicAdd(&stats[9 + k], (double)s2);
        }
    }
}

// ============================================================================
// FALLBACK PATH (round-1 algorithm, used only if ws_size too small)
// ============================================================================

__global__ __launch_bounds__(256) void edge_kernel(
        const int* __restrict__ edge,
        const float* __restrict__ sp,
        const float* __restrict__ qp,
        float* __restrict__ acc) {
    int e = blockIdx.x * 256 + threadIdx.x;
    if (e >= N_EDGES) return;
    int q = edge[e];
    int s = edge[N_EDGES + e];
    float sx = sp[3 * s + 0], sy = sp[3 * s + 1], sz = sp[3 * s + 2];
    float qx = qp[3 * q + 0], qy = qp[3 * q + 1], qz = qp[3 * q + 2];
    float dx = sx - qx, dy = sy - qy, dz = sz - qz;
    float d2 = dx * dx + dy * dy + dz * dz;
    atomAddF(acc + 0 * Q_NODES + q, 1.0f);
    atomAddF(acc + 1 * Q_NODES + q, sqrtf(d2));
    atomAddF(acc + 2 * Q_NODES + q, d2);
    atomAddF(acc + 3 * Q_NODES + q, sx);
    atomAddF(acc + 4 * Q_NODES + q, sy);
    atomAddF(acc + 5 * Q_NODES + q, sz);
    atomAddF(acc + 6 * Q_NODES + q, sx * sx);
    atomAddF(acc + 7 * Q_NODES + q, sx * sy);
    atomAddF(acc + 8 * Q_NODES + q, sx * sz);
    atomAddF(acc + 9 * Q_NODES + q, sy * sy);
    atomAddF(acc + 10 * Q_NODES + q, sy * sz);
    atomAddF(acc + 11 * Q_NODES + q, sz * sz);
}

__global__ __launch_bounds__(256) void finalize_kernel(
        const float* __restrict__ acc,
        const float* __restrict__ qp,
        float* __restrict__ feats,
        double* __restrict__ stats) {
    int q = blockIdx.x * 256 + threadIdx.x;
    float f[9];
#pragma unroll
    for (int k = 0; k < 9; ++k) f[k] = 0.0f;
    if (q < Q_NODES) {
        float s[12];
#pragma unroll
        for (int k = 0; k < 12; ++k) s[k] = acc[k * Q_NODES + q];
        float qx = qp[3 * q + 0], qy = qp[3 * q + 1], qz = qp[3 * q + 2];
        sums_to_feats(s, qx, qy, qz, f);
#pragma unroll
        for (int k = 0; k < 9; ++k) feats[k * Q_NODES + q] = f[k];
    }
    int lane = threadIdx.x & 63;
#pragma unroll
    for (int k = 0; k < 9; ++k) {
        float s1 = f[k];
        float s2 = f[k] * f[k];
#pragma unroll
        for (int off = 32; off > 0; off >>= 1) {
            s1 += __shfl_down(s1, off);
            s2 += __shfl_down(s2, off);
        }
        if (lane == 0) {
            atomicAdd(&stats[k], (double)s1);
            atomicAdd(&stats[9 + k], (double)s2);
        }
    }
}

// ============================================================================
// Shared tail kernels
// ============================================================================

__global__ void stats_kernel(const double* __restrict__ stats,
                             float* __restrict__ norm) {
    int k = threadIdx.x;
    if (k < 9) {
        double S = stats[k], S2 = stats[9 + k];
        double mean = S / (double)Q_NODES;
        double var = (S2 - S * S / (double)Q_NODES) / (double)(Q_NODES - 1);
        if (var < 0.0) var = 0.0;
        double sd = sqrt(var);
        if (sd < 1e-6) sd = 1.0;
        norm[k] = (float)mean;
        norm[9 + k] = (float)(1.0 / sd);
    }
}

__global__ __launch_bounds__(256) void mlp_kernel(
        const float* __restrict__ feats,
        const float* __restrict__ norm,
        const float* __restrict__ W1, const float* __restrict__ b1,
        const float* __restrict__ W2, const float* __restrict__ b2,
        float* __restrict__ out) {
    __shared__ float sm[576 + 64 + 8192 + 128 + 18];
    float* sW1 = sm;                 // [64][9]
    float* sB1 = sm + 576;           // [64]
    float* sW2 = sm + 640;           // [128][64]
    float* sB2 = sm + 8832;          // [128]
    float* sNorm = sm + 8960;        // [18]

    for (int i = threadIdx.x; i < 576; i += 256) sW1[i] = W1[i];
    if (threadIdx.x < 64) sB1[threadIdx.x] = b1[threadIdx.x];
    for (int i = threadIdx.x; i < 8192; i += 256) sW2[i] = W2[i];
    if (threadIdx.x < 128) sB2[threadIdx.x] = b2[threadIdx.x];
    if (threadIdx.x < 18) sNorm[threadIdx.x] = norm[threadIdx.x];
    __syncthreads();

    int q = blockIdx.x * 256 + threadIdx.x;
    bool valid = q < Q_NODES;
    int qq = valid ? q : 0;

    float f[9];
#pragma unroll
    for (int k = 0; k < 9; ++k)
        f[k] = (feats[k * Q_NODES + qq] - sNorm[k]) * sNorm[9 + k];

    float h[64];
#pragma unroll
    for (int j = 0; j < 64; ++j) {
        float a = sB1[j];
#pragma unroll
        for (int k = 0; k < 9; ++k) a = fmaf(f[k], sW1[j * 9 + k], a);
        h[j] = fmaxf(a, 0.0f);
    }

    if (!valid) return;
    float* op = out + (size_t)q * 128;
#pragma unroll 1
    for (int o = 0; o < 128; o += 4) {
        float a0 = sB2[o + 0], a1 = sB2[o + 1], a2 = sB2[o + 2], a3 = sB2[o + 3];
#pragma unroll
        for (int j = 0; j < 64; j += 4) {
            float4 w0 = *(const float4*)&sW2[(o + 0) * 64 + j];
            float4 w1 = *(const float4*)&sW2[(o + 1) * 64 + j];
            float4 w2 = *(const float4*)&sW2[(o + 2) * 64 + j];
            float4 w3 = *(const float4*)&sW2[(o + 3) * 64 + j];
            float h0 = h[j], h1 = h[j + 1], h2 = h[j + 2], h3 = h[j + 3];
            a0 = fmaf(h0, w0.x, a0); a0 = fmaf(h1, w0.y, a0); a0 = fmaf(h2, w0.z, a0); a0 = fmaf(h3, w0.w, a0);
            a1 = fmaf(h0, w1.x, a1); a1 = fmaf(h1, w1.y, a1); a1 = fmaf(h2, w1.z, a1); a1 = fmaf(h3, w1.w, a1);
            a2 = fmaf(h0, w2.x, a2); a2 = fmaf(h1, w2.y, a2); a2 = fmaf(h2, w2.z, a2); a2 = fmaf(h3, w2.w, a2);
            a3 = fmaf(h0, w3.x, a3); a3 = fmaf(h1, w3.y, a3); a3 = fmaf(h2, w3.z, a3); a3 = fmaf(h3, w3.w, a3);
        }
        float4 vv = make_float4(a0, a1, a2, a3);
        *(float4*)(op + o) = vv;
    }
}

// ============================================================================

extern "C" void kernel_launch(void* const* d_in, const int* in_sizes, int n_in,
                              void* d_out, int out_size, void* d_ws, size_t ws_size,
                              hipStream_t stream) {
    const float* sp   = (const float*)d_in[0];
    const float* qp   = (const float*)d_in[1];
    const int*   edge = (const int*)d_in[2];
    const float* W1   = (const float*)d_in[3];
    const float* b1   = (const float*)d_in[4];
    const float* W2   = (const float*)d_in[5];
    const float* b2   = (const float*)d_in[6];
    float* out = (float*)d_out;
    char* ws = (char*)d_ws;

    if (ws_size >= F_WS_NEED) {
        int*          cursor = (int*)(ws + F_CURSOR_OFF);
        double*       stats  = (double*)(ws + F_STATS_OFF);
        float*        norm   = (float*)(ws + F_NORM_OFF);
        float*        feats  = (float*)(ws + F_FEATS_OFF);
        unsigned int* slots  = (unsigned int*)(ws + F_SLOTS_OFF);

        hipMemsetAsync(ws, 0, F_ZERO_BYTES, stream);
        partition_kernel<<<(N_EDGES + TILE - 1) / TILE, 256, 0, stream>>>(edge, cursor, slots);
        bucket_kernel<<<NB, 256, 0, stream>>>(cursor, slots, sp, qp, feats, stats);
        stats_kernel<<<1, 64, 0, stream>>>(stats, norm);
        mlp_kernel<<<(Q_NODES + 255) / 256, 256, 0, stream>>>(feats, norm, W1, b1, W2, b2, out);
    } else {
        float*  acc   = (float*)(ws + B_ACC_OFF);
        double* stats = (double*)(ws + B_STATS_OFF);
        float*  norm  = (float*)(ws + B_NORM_OFF);
        float*  feats = (float*)(ws + B_FEATS_OFF);

        hipMemsetAsync(ws, 0, B_ZERO_BYTES, stream);
        edge_kernel<<<N_EDGES / 256, 256, 0, stream>>>(edge, sp, qp, acc);
        finalize_kernel<<<(Q_NODES + 255) / 256, 256, 0, stream>>>(acc, qp, feats, stats);
        stats_kernel<<<1, 64, 0, stream>>>(stats, norm);
        mlp_kernel<<<(Q_NODES + 255) / 256, 256, 0, stream>>>(feats, norm, W1, b1, W2, b2, out);
    }
}

// Round 4
// 540.862 us; speedup vs baseline: 4.0225x; 1.2226x over previous
//
#include <hip/hip_runtime.h>
#include <math.h>

#define Q_NODES 100000
#define S_NODES 100000
#define N_EDGES 3200000
#define HIDDEN 64
#define OUT_DIM 128

// ---------- bucket partition parameters ----------
#define QPB   128                    // queries per bucket (bucket = q >> 7)
#define NB    782                    // ceil(Q_NODES / QPB)
#define CAPB  4608                   // bucket capacity: mean 4096, +8 sigma
#define TILE  4096                   // edges per partition block
#define NT4   (N_EDGES / 4)          // int4 count per edge row

// ---------- FAST-PATH workspace layout (bytes) ----------
//   [0,       3128)      cursor : NB ints (per-bucket fill count)
//   [3200,    3344)      stats  : 18 doubles (sum[9], sumsq[9])
//   [3360,    3432)      norm   : 18 floats (mean[9], inv_std[9])
//   [3456,    3603456)   feats  : 9 * Q floats (SoA)
//   [3603456, 5203456)   sp4    : S_NODES float4 (padded source_pos)
//   [5203456, ...)       slots  : NB*CAPB+1 uint32 packed records (qlow<<17|s), +1 dump
#define F_CURSOR_OFF 0
#define F_STATS_OFF  3200
#define F_NORM_OFF   3360
#define F_FEATS_OFF  3456
#define F_SP4_OFF    3603456
#define F_SLOTS_OFF  5203456
#define F_ZERO_BYTES 3344            // cursor + stats
#define F_WS_NEED    (5203456ull + (unsigned long long)(NB * CAPB + 1) * 4)

// ---------- FALLBACK workspace layout (round-1 algorithm) ----------
#define B_ACC_OFF    0
#define B_STATS_OFF  4800000
#define B_NORM_OFF   4800144
#define B_FEATS_OFF  4800224
#define B_ZERO_BYTES 4800144

__device__ __forceinline__ void atomAddF(float* p, float v) {
#if defined(__gfx950__) || defined(__gfx942__) || defined(__gfx90a__)
    unsafeAtomicAdd(p, v);
#else
    atomicAdd(p, v);
#endif
}

// ============================================================================
// Shared device helpers
// ============================================================================

// 3x3 symmetric eigenvalues (Smith's trig method), descending e1>=e2>=e3.
__device__ __forceinline__ void eig3_sym(
        float a00, float a01, float a02, float a11, float a12, float a22,
        float& e1, float& e2, float& e3) {
    float p1 = a01 * a01 + a02 * a02 + a12 * a12;
    float qm = (a00 + a11 + a22) * (1.0f / 3.0f);
    float b00 = a00 - qm, b11 = a11 - qm, b22 = a22 - qm;
    float p2 = b00 * b00 + b11 * b11 + b22 * b22 + 2.0f * p1;
    if (p2 <= 1e-24f) {
        e1 = qm; e2 = qm; e3 = qm;
    } else {
        float p = sqrtf(p2 * (1.0f / 6.0f));
        float invp = 1.0f / p;
        float c00 = b00 * invp, c11 = b11 * invp, c22 = b22 * invp;
        float c01 = a01 * invp, c02 = a02 * invp, c12 = a12 * invp;
        float detB = c00 * (c11 * c22 - c12 * c12)
                   - c01 * (c01 * c22 - c12 * c02)
                   + c02 * (c01 * c12 - c11 * c02);
        float r = 0.5f * detB;
        r = fminf(fmaxf(r, -1.0f), 1.0f);
        float phi = acosf(r) * (1.0f / 3.0f);
        e1 = qm + 2.0f * p * cosf(phi);
        e3 = qm + 2.0f * p * cosf(phi + 2.0943951023931953f); // +2pi/3
        e2 = 3.0f * qm - e1 - e3;
    }
}

// sums: n,sumd,sumd2,sx,sy,sz,xx,xy,xz,yy,yz,zz -> 9 features
__device__ __forceinline__ void sums_to_feats(
        const float* s, float qx, float qy, float qz, float* f) {
    float n = s[0];
#pragma unroll
    for (int k = 0; k < 9; ++k) f[k] = 0.0f;
    if (n > 0.0f) {
        float inv = 1.0f / n;
        float Davg = s[1] * inv;
        float Dvar = fmaxf(s[2] * inv - Davg * Davg, 0.0f);
        float cx = s[3] * inv, cy = s[4] * inv, cz = s[5] * inv;
        float a00 = fmaxf(s[6] * inv - cx * cx, 0.0f);
        float a01 = s[7] * inv - cx * cy;
        float a02 = s[8] * inv - cx * cz;
        float a11 = fmaxf(s[9] * inv - cy * cy, 0.0f);
        float a12 = s[10] * inv - cy * cz;
        float a22 = fmaxf(s[11] * inv - cz * cz, 0.0f);
        float e1, e2, e3;
        eig3_sym(a00, a01, a02, a11, a12, a22, e1, e2, e3);
        f[0] = n; f[1] = Davg; f[2] = Dvar;
        f[3] = cx - qx; f[4] = cy - qy; f[5] = cz - qz;
        f[6] = e1; f[7] = e2; f[8] = e3;
    }
}

// ============================================================================
// FAST PATH
// ============================================================================

__global__ __launch_bounds__(256) void pad_kernel(
        const float* __restrict__ sp, float4* __restrict__ sp4) {
    int i = blockIdx.x * 256 + threadIdx.x;
    if (i < S_NODES) sp4[i] = make_float4(sp[3 * i], sp[3 * i + 1], sp[3 * i + 2], 0.0f);
}

__global__ __launch_bounds__(256) void partition_kernel(
        const int* __restrict__ edge,
        int* __restrict__ cursor,
        unsigned int* __restrict__ slots) {
    __shared__ unsigned int s_rec[TILE];   // 16 KB: packed records, bucket-sorted
    __shared__ int s_pos[TILE];            // 16 KB: global dest index per record
    __shared__ int s_hist[NB];
    __shared__ int s_cur[NB];              // pref during scan, then scatter cursor
    __shared__ int s_off[NB];              // bkt*CAPB + base - pref
    __shared__ int s_wsum[4];

    int tid = threadIdx.x;
    int lane = tid & 63, wv = tid >> 6;
    int tileStart = blockIdx.x * TILE;
    int tileCount = N_EDGES - tileStart;
    if (tileCount > TILE) tileCount = TILE;

    for (int b = tid; b < NB; b += 256) s_hist[b] = 0;
    __syncthreads();

    const int4* eq4 = (const int4*)edge;
    const int4* es4 = (const int4*)(edge + N_EDGES);
    int base4 = blockIdx.x * (TILE / 4);
    int4 q4[4], s4[4];
    bool v[4];
#pragma unroll
    for (int j = 0; j < 4; ++j) {
        int i4 = base4 + tid + j * 256;
        v[j] = i4 < NT4;
        int ic = v[j] ? i4 : 0;
        q4[j] = eq4[ic];
        s4[j] = es4[ic];
        if (v[j]) {
            atomicAdd(&s_hist[q4[j].x >> 7], 1);
            atomicAdd(&s_hist[q4[j].y >> 7], 1);
            atomicAdd(&s_hist[q4[j].z >> 7], 1);
            atomicAdd(&s_hist[q4[j].w >> 7], 1);
        }
    }
    __syncthreads();

    // exclusive prefix of s_hist -> s_cur, via per-thread 4-sum + wave shfl scan
    int local[4], tsum = 0;
#pragma unroll
    for (int j = 0; j < 4; ++j) {
        int idx = 4 * tid + j;
        local[j] = (idx < NB) ? s_hist[idx] : 0;
        tsum += local[j];
    }
    int inc = tsum;
#pragma unroll
    for (int off = 1; off < 64; off <<= 1) {
        int t = __shfl_up(inc, off);
        if (lane >= off) inc += t;
    }
    if (lane == 63) s_wsum[wv] = inc;
    __syncthreads();
    int wbase = 0;
    for (int w = 0; w < wv; ++w) wbase += s_wsum[w];
    int run = wbase + inc - tsum;
#pragma unroll
    for (int j = 0; j < 4; ++j) {
        int idx = 4 * tid + j;
        if (idx < NB) s_cur[idx] = run;
        run += local[j];
    }
    __syncthreads();

    // reserve global space per non-empty bucket; s_off maps LDS idx -> global idx
    for (int b = tid; b < NB; b += 256) {
        int c = s_hist[b];
        int base = c ? atomicAdd(&cursor[b], c) : 0;
        s_off[b] = b * CAPB + base - s_cur[b];
    }
    __syncthreads();

    // scatter into bucket-sorted LDS stage, computing global dest on the fly
#pragma unroll
    for (int j = 0; j < 4; ++j) {
        if (v[j]) {
            int qs[4] = { q4[j].x, q4[j].y, q4[j].z, q4[j].w };
            int ss[4] = { s4[j].x, s4[j].y, s4[j].z, s4[j].w };
#pragma unroll
            for (int m = 0; m < 4; ++m) {
                int bkt = qs[m] >> 7;
                int idx = atomicAdd(&s_cur[bkt], 1);
                int gpos = idx + s_off[bkt];
                if (gpos >= (bkt + 1) * CAPB) gpos = NB * CAPB;  // dump slot (overflow guard)
                s_rec[idx] = ((unsigned)(qs[m] & (QPB - 1)) << 17) | (unsigned)ss[m];
                s_pos[idx] = gpos;
            }
        }
    }
    __syncthreads();

    // write-out: bucket-contiguous runs -> mostly coalesced
    for (int i = tid; i < tileCount; i += 256)
        slots[s_pos[i]] = s_rec[i];
}

__global__ __launch_bounds__(256) void bucket_kernel(
        const int* __restrict__ cursor,
        const unsigned int* __restrict__ slots,
        const float4* __restrict__ sp4,
        const float* __restrict__ qp,
        float* __restrict__ feats,
        double* __restrict__ stats) {
    __shared__ unsigned int s_sorted[CAPB];   // 18 KB
    __shared__ float qtile[QPB * 3];
    __shared__ int s_cnt[QPB], s_start[QPB], s_cur[QPB];

    int tid = threadIdx.x;
    int b = blockIdx.x;
    int cnt = cursor[b];
    if (cnt > CAPB) cnt = CAPB;

    if (tid < QPB) s_cnt[tid] = 0;
    for (int i = tid; i < QPB * 3; i += 256) {
        int g = b * QPB * 3 + i;
        qtile[i] = (g < Q_NODES * 3) ? qp[g] : 0.0f;
    }
    __syncthreads();

    const unsigned int* bslots = slots + b * CAPB;
    // histogram by query-within-bucket (random addresses -> low contention)
    for (int i = tid; i < cnt; i += 256)
        atomicAdd(&s_cnt[bslots[i] >> 17], 1);
    __syncthreads();

    // exclusive scan of 128 counts by wave 0 (2 elements/lane, shfl scan)
    if (tid < 64) {
        int a0 = s_cnt[tid], a1 = s_cnt[64 + tid];
        int i0 = a0, i1 = a1;
#pragma unroll
        for (int off = 1; off < 64; off <<= 1) {
            int t0 = __shfl_up(i0, off); if (tid >= off) i0 += t0;
            int t1 = __shfl_up(i1, off); if (tid >= off) i1 += t1;
        }
        int tot0 = __shfl(i0, 63);
        s_start[tid] = i0 - a0;              s_cur[tid] = i0 - a0;
        s_start[64 + tid] = i1 - a1 + tot0;  s_cur[64 + tid] = i1 - a1 + tot0;
    }
    __syncthreads();

    // counting-sort scatter into LDS
    for (int i = tid; i < cnt; i += 256) {
        unsigned rec = bslots[i];
        int pos = atomicAdd(&s_cur[rec >> 17], 1);
        s_sorted[pos] = rec;
    }
    __syncthreads();

    // per-query register accumulate: thread t owns query t (zero atomics)
    float f[9];
#pragma unroll
    for (int k = 0; k < 9; ++k) f[k] = 0.0f;
    int q = b * QPB + tid;
    if (tid < QPB && q < Q_NODES) {
        float qx = qtile[3 * tid + 0], qy = qtile[3 * tid + 1], qz = qtile[3 * tid + 2];
        float s[12];
#pragma unroll
        for (int k = 0; k < 12; ++k) s[k] = 0.0f;
        int st = s_start[tid], deg = s_cnt[tid];
        for (int j = 0; j < deg; ++j) {
            unsigned rec = s_sorted[st + j];
            float4 sv = sp4[rec & 0x1FFFF];
            float dx = sv.x - qx, dy = sv.y - qy, dz = sv.z - qz;
            float d2 = dx * dx + dy * dy + dz * dz;
            s[0] += 1.0f;
            s[1] += sqrtf(d2);
            s[2] += d2;
            s[3] += sv.x; s[4] += sv.y; s[5] += sv.z;
            s[6] += sv.x * sv.x; s[7] += sv.x * sv.y; s[8] += sv.x * sv.z;
            s[9] += sv.y * sv.y; s[10] += sv.y * sv.z; s[11] += sv.z * sv.z;
        }
        sums_to_feats(s, qx, qy, qz, f);
#pragma unroll
        for (int k = 0; k < 9; ++k) feats[k * Q_NODES + q] = f[k];  // coalesced per k
    }

    // dataset-wide stats: wave reduce, lane0 double-atomic (inactive threads add 0)
    int lane = tid & 63;
#pragma unroll
    for (int k = 0; k < 9; ++k) {
        float s1 = f[k];
        float s2 = f[k] * f[k];
#pragma unroll
        for (int off = 32; off > 0; off >>= 1) {
            s1 += __shfl_down(s1, off);
            s2 += __shfl_down(s2, off);
        }
        if (lane == 0) {
            atomicAdd(&stats[k], (double)s1);
            atomicAdd(&stats[9 + k], (double)s2);
        }
    }
}

// ============================================================================
// FALLBACK PATH (round-1 algorithm, used only if ws_size too small)
// ============================================================================

__global__ __launch_bounds__(256) void edge_kernel(
        const int* __restrict__ edge,
        const float* __restrict__ sp,
        const float* __restrict__ qp,
        float* __restrict__ acc) {
    int e = blockIdx.x * 256 + threadIdx.x;
    if (e >= N_EDGES) return;
    int q = edge[e];
    int s = edge[N_EDGES + e];
    float sx = sp[3 * s + 0], sy = sp[3 * s + 1], sz = sp[3 * s + 2];
    float qx = qp[3 * q + 0], qy = qp[3 * q + 1], qz = qp[3 * q + 2];
    float dx = sx - qx, dy = sy - qy, dz = sz - qz;
    float d2 = dx * dx + dy * dy + dz * dz;
    atomAddF(acc + 0 * Q_NODES + q, 1.0f);
    atomAddF(acc + 1 * Q_NODES + q, sqrtf(d2));
    atomAddF(acc + 2 * Q_NODES + q, d2);
    atomAddF(acc + 3 * Q_NODES + q, sx);
    atomAddF(acc + 4 * Q_NODES + q, sy);
    atomAddF(acc + 5 * Q_NODES + q, sz);
    atomAddF(acc + 6 * Q_NODES + q, sx * sx);
    atomAddF(acc + 7 * Q_NODES + q, sx * sy);
    atomAddF(acc + 8 * Q_NODES + q, sx * sz);
    atomAddF(acc + 9 * Q_NODES + q, sy * sy);
    atomAddF(acc + 10 * Q_NODES + q, sy * sz);
    atomAddF(acc + 11 * Q_NODES + q, sz * sz);
}

__global__ __launch_bounds__(256) void finalize_kernel(
        const float* __restrict__ acc,
        const float* __restrict__ qp,
        float* __restrict__ feats,
        double* __restrict__ stats) {
    int q = blockIdx.x * 256 + threadIdx.x;
    float f[9];
#pragma unroll
    for (int k = 0; k < 9; ++k) f[k] = 0.0f;
    if (q < Q_NODES) {
        float s[12];
#pragma unroll
        for (int k = 0; k < 12; ++k) s[k] = acc[k * Q_NODES + q];
        float qx = qp[3 * q + 0], qy = qp[3 * q + 1], qz = qp[3 * q + 2];
        sums_to_feats(s, qx, qy, qz, f);
#pragma unroll
        for (int k = 0; k < 9; ++k) feats[k * Q_NODES + q] = f[k];
    }
    int lane = threadIdx.x & 63;
#pragma unroll
    for (int k = 0; k < 9; ++k) {
        float s1 = f[k];
        float s2 = f[k] * f[k];
#pragma unroll
        for (int off = 32; off > 0; off >>= 1) {
            s1 += __shfl_down(s1, off);
            s2 += __shfl_down(s2, off);
        }
        if (lane == 0) {
            atomicAdd(&stats[k], (double)s1);
            atomicAdd(&stats[9 + k], (double)s2);
        }
    }
}

// ============================================================================
// Shared tail kernels
// ============================================================================

__global__ void stats_kernel(const double* __restrict__ stats,
                             float* __restrict__ norm) {
    int k = threadIdx.x;
    if (k < 9) {
        double S = stats[k], S2 = stats[9 + k];
        double mean = S / (double)Q_NODES;
        double var = (S2 - S * S / (double)Q_NODES) / (double)(Q_NODES - 1);
        if (var < 0.0) var = 0.0;
        double sd = sqrt(var);
        if (sd < 1e-6) sd = 1.0;
        norm[k] = (float)mean;
        norm[9 + k] = (float)(1.0 / sd);
    }
}

__global__ __launch_bounds__(256) void mlp_kernel(
        const float* __restrict__ feats,
        const float* __restrict__ norm,
        const float* __restrict__ W1, const float* __restrict__ b1,
        const float* __restrict__ W2, const float* __restrict__ b2,
        float* __restrict__ out) {
    __shared__ float sm[576 + 64 + 8192 + 128 + 18];
    float* sW1 = sm;                 // [64][9]
    float* sB1 = sm + 576;           // [64]
    float* sW2 = sm + 640;           // [128][64]
    float* sB2 = sm + 8832;          // [128]
    float* sNorm = sm + 8960;        // [18]

    for (int i = threadIdx.x; i < 576; i += 256) sW1[i] = W1[i];
    if (threadIdx.x < 64) sB1[threadIdx.x] = b1[threadIdx.x];
    for (int i = threadIdx.x; i < 8192; i += 256) sW2[i] = W2[i];
    if (threadIdx.x < 128) sB2[threadIdx.x] = b2[threadIdx.x];
    if (threadIdx.x < 18) sNorm[threadIdx.x] = norm[threadIdx.x];
    __syncthreads();

    int q = blockIdx.x * 256 + threadIdx.x;
    bool valid = q < Q_NODES;
    int qq = valid ? q : 0;

    float f[9];
#pragma unroll
    for (int k = 0; k < 9; ++k)
        f[k] = (feats[k * Q_NODES + qq] - sNorm[k]) * sNorm[9 + k];

    float h[64];
#pragma unroll
    for (int j = 0; j < 64; ++j) {
        float a = sB1[j];
#pragma unroll
        for (int k = 0; k < 9; ++k) a = fmaf(f[k], sW1[j * 9 + k], a);
        h[j] = fmaxf(a, 0.0f);
    }

    if (!valid) return;
    float* op = out + (size_t)q * 128;
#pragma unroll 1
    for (int o = 0; o < 128; o += 4) {
        float a0 = sB2[o + 0], a1 = sB2[o + 1], a2 = sB2[o + 2], a3 = sB2[o + 3];
#pragma unroll
        for (int j = 0; j < 64; j += 4) {
            float4 w0 = *(const float4*)&sW2[(o + 0) * 64 + j];
            float4 w1 = *(const float4*)&sW2[(o + 1) * 64 + j];
            float4 w2 = *(const float4*)&sW2[(o + 2) * 64 + j];
            float4 w3 = *(const float4*)&sW2[(o + 3) * 64 + j];
            float h0 = h[j], h1 = h[j + 1], h2 = h[j + 2], h3 = h[j + 3];
            a0 = fmaf(h0, w0.x, a0); a0 = fmaf(h1, w0.y, a0); a0 = fmaf(h2, w0.z, a0); a0 = fmaf(h3, w0.w, a0);
            a1 = fmaf(h0, w1.x, a1); a1 = fmaf(h1, w1.y, a1); a1 = fmaf(h2, w1.z, a1); a1 = fmaf(h3, w1.w, a1);
            a2 = fmaf(h0, w2.x, a2); a2 = fmaf(h1, w2.y, a2); a2 = fmaf(h2, w2.z, a2); a2 = fmaf(h3, w2.w, a2);
            a3 = fmaf(h0, w3.x, a3); a3 = fmaf(h1, w3.y, a3); a3 = fmaf(h2, w3.z, a3); a3 = fmaf(h3, w3.w, a3);
        }
        float4 vv = make_float4(a0, a1, a2, a3);
        *(float4*)(op + o) = vv;
    }
}

// ============================================================================

extern "C" void kernel_launch(void* const* d_in, const int* in_sizes, int n_in,
                              void* d_out, int out_size, void* d_ws, size_t ws_size,
                              hipStream_t stream) {
    const float* sp   = (const float*)d_in[0];
    const float* qp   = (const float*)d_in[1];
    const int*   edge = (const int*)d_in[2];
    const float* W1   = (const float*)d_in[3];
    const float* b1   = (const float*)d_in[4];
    const float* W2   = (const float*)d_in[5];
    const float* b2   = (const float*)d_in[6];
    float* out = (float*)d_out;
    char* ws = (char*)d_ws;

    if (ws_size >= F_WS_NEED) {
        int*          cursor = (int*)(ws + F_CURSOR_OFF);
        double*       stats  = (double*)(ws + F_STATS_OFF);
        float*        norm   = (float*)(ws + F_NORM_OFF);
        float*        feats  = (float*)(ws + F_FEATS_OFF);
        float4*       sp4    = (float4*)(ws + F_SP4_OFF);
        unsigned int* slots  = (unsigned int*)(ws + F_SLOTS_OFF);

        hipMemsetAsync(ws, 0, F_ZERO_BYTES, stream);
        pad_kernel<<<(S_NODES + 255) / 256, 256, 0, stream>>>(sp, sp4);
        partition_kernel<<<(N_EDGES + TILE - 1) / TILE, 256, 0, stream>>>(edge, cursor, slots);
        bucket_kernel<<<NB, 256, 0, stream>>>(cursor, slots, sp4, qp, feats, stats);
        stats_kernel<<<1, 64, 0, stream>>>(stats, norm);
        mlp_kernel<<<(Q_NODES + 255) / 256, 256, 0, stream>>>(feats, norm, W1, b1, W2, b2, out);
    } else {
        float*  acc   = (float*)(ws + B_ACC_OFF);
        double* stats = (double*)(ws + B_STATS_OFF);
        float*  norm  = (float*)(ws + B_NORM_OFF);
        float*  feats = (float*)(ws + B_FEATS_OFF);

        hipMemsetAsync(ws, 0, B_ZERO_BYTES, stream);
        edge_kernel<<<N_EDGES / 256, 256, 0, stream>>>(edge, sp, qp, acc);
        finalize_kernel<<<(Q_NODES + 255) / 256, 256, 0, stream>>>(acc, qp, feats, stats);
        stats_kernel<<<1, 64, 0, stream>>>(stats, norm);
        mlp_kernel<<<(Q_NODES + 255) / 256, 256, 0, stream>>>(feats, norm, W1, b1, W2, b2, out);
    }
}

// Round 5
// 257.529 us; speedup vs baseline: 8.4480x; 2.1002x over previous
//
#include <hip/hip_runtime.h>
#include <math.h>

#define Q_NODES 100000
#define S_NODES 100000
#define N_EDGES 3200000
#define HIDDEN 64
#define OUT_DIM 128

// ---------- bucket partition parameters ----------
#define QPB   128                    // queries per bucket (bucket = q >> 7)
#define NB    782                    // ceil(Q_NODES / QPB)
#define CAPB  4608                   // bucket capacity: mean 4096, +8 sigma
#define TILE  4096                   // edges per partition block
#define NT4   (N_EDGES / 4)          // int4 count per edge row

// ---------- FAST-PATH workspace layout (bytes) ----------
//   [0,       3128)      cursor : NB ints (per-bucket fill count)
//   [3200,    3272)      norm   : 18 floats (mean[9], inv_std[9])
//   [3328,    31480)     psum   : 9*NB floats (per-block partial sums, col-major)
//   [31488,   59640)     psumsq : 9*NB floats (per-block partial sumsq)
//   [59648,   3659648)   feats  : 9 * Q floats (SoA)
//   [3659648, 5259648)   sp4    : S_NODES float4 (padded source_pos)
//   [5259648, ...)       slots  : NB*CAPB+1 uint32 packed records (qlow<<17|s), +1 dump
#define F_CURSOR_OFF 0
#define F_NORM_OFF   3200
#define F_PSUM_OFF   3328
#define F_PSUMSQ_OFF 31488
#define F_FEATS_OFF  59648
#define F_SP4_OFF    3659648
#define F_SLOTS_OFF  5259648
#define F_ZERO_BYTES 3200            // cursor only
#define F_WS_NEED    (5259648ull + (unsigned long long)(NB * CAPB + 1) * 4)

// ---------- FALLBACK workspace layout (round-1 algorithm) ----------
#define B_ACC_OFF    0
#define B_STATS_OFF  4800000
#define B_NORM_OFF   4800144
#define B_FEATS_OFF  4800224
#define B_ZERO_BYTES 4800144

__device__ __forceinline__ void atomAddF(float* p, float v) {
#if defined(__gfx950__) || defined(__gfx942__) || defined(__gfx90a__)
    unsafeAtomicAdd(p, v);
#else
    atomicAdd(p, v);
#endif
}

// ============================================================================
// Shared device helpers
// ============================================================================

// 3x3 symmetric eigenvalues (Smith's trig method), descending e1>=e2>=e3.
__device__ __forceinline__ void eig3_sym(
        float a00, float a01, float a02, float a11, float a12, float a22,
        float& e1, float& e2, float& e3) {
    float p1 = a01 * a01 + a02 * a02 + a12 * a12;
    float qm = (a00 + a11 + a22) * (1.0f / 3.0f);
    float b00 = a00 - qm, b11 = a11 - qm, b22 = a22 - qm;
    float p2 = b00 * b00 + b11 * b11 + b22 * b22 + 2.0f * p1;
    if (p2 <= 1e-24f) {
        e1 = qm; e2 = qm; e3 = qm;
    } else {
        float p = sqrtf(p2 * (1.0f / 6.0f));
        float invp = 1.0f / p;
        float c00 = b00 * invp, c11 = b11 * invp, c22 = b22 * invp;
        float c01 = a01 * invp, c02 = a02 * invp, c12 = a12 * invp;
        float detB = c00 * (c11 * c22 - c12 * c12)
                   - c01 * (c01 * c22 - c12 * c02)
                   + c02 * (c01 * c12 - c11 * c02);
        float r = 0.5f * detB;
        r = fminf(fmaxf(r, -1.0f), 1.0f);
        float phi = acosf(r) * (1.0f / 3.0f);
        e1 = qm + 2.0f * p * cosf(phi);
        e3 = qm + 2.0f * p * cosf(phi + 2.0943951023931953f); // +2pi/3
        e2 = 3.0f * qm - e1 - e3;
    }
}

// sums: n,sumd,sumd2,sx,sy,sz,xx,xy,xz,yy,yz,zz -> 9 features
__device__ __forceinline__ void sums_to_feats(
        const float* s, float qx, float qy, float qz, float* f) {
    float n = s[0];
#pragma unroll
    for (int k = 0; k < 9; ++k) f[k] = 0.0f;
    if (n > 0.0f) {
        float inv = 1.0f / n;
        float Davg = s[1] * inv;
        float Dvar = fmaxf(s[2] * inv - Davg * Davg, 0.0f);
        float cx = s[3] * inv, cy = s[4] * inv, cz = s[5] * inv;
        float a00 = fmaxf(s[6] * inv - cx * cx, 0.0f);
        float a01 = s[7] * inv - cx * cy;
        float a02 = s[8] * inv - cx * cz;
        float a11 = fmaxf(s[9] * inv - cy * cy, 0.0f);
        float a12 = s[10] * inv - cy * cz;
        float a22 = fmaxf(s[11] * inv - cz * cz, 0.0f);
        float e1, e2, e3;
        eig3_sym(a00, a01, a02, a11, a12, a22, e1, e2, e3);
        f[0] = n; f[1] = Davg; f[2] = Dvar;
        f[3] = cx - qx; f[4] = cy - qy; f[5] = cz - qz;
        f[6] = e1; f[7] = e2; f[8] = e3;
    }
}

// ============================================================================
// FAST PATH
// ============================================================================

__global__ __launch_bounds__(256) void pad_kernel(
        const float* __restrict__ sp, float4* __restrict__ sp4) {
    int i = blockIdx.x * 256 + threadIdx.x;
    if (i < S_NODES) sp4[i] = make_float4(sp[3 * i], sp[3 * i + 1], sp[3 * i + 2], 0.0f);
}

__global__ __launch_bounds__(256) void partition_kernel(
        const int* __restrict__ edge,
        int* __restrict__ cursor,
        unsigned int* __restrict__ slots) {
    __shared__ unsigned int s_rec[TILE];   // 16 KB: packed records, bucket-sorted
    __shared__ int s_pos[TILE];            // 16 KB: global dest index per record
    __shared__ int s_hist[NB];
    __shared__ int s_cur[NB];              // pref during scan, then scatter cursor
    __shared__ int s_off[NB];              // bkt*CAPB + base - pref
    __shared__ int s_wsum[4];

    int tid = threadIdx.x;
    int lane = tid & 63, wv = tid >> 6;
    int tileStart = blockIdx.x * TILE;
    int tileCount = N_EDGES - tileStart;
    if (tileCount > TILE) tileCount = TILE;

    for (int b = tid; b < NB; b += 256) s_hist[b] = 0;
    __syncthreads();

    const int4* eq4 = (const int4*)edge;
    const int4* es4 = (const int4*)(edge + N_EDGES);
    int base4 = blockIdx.x * (TILE / 4);
    int4 q4[4], s4[4];
    bool v[4];
#pragma unroll
    for (int j = 0; j < 4; ++j) {
        int i4 = base4 + tid + j * 256;
        v[j] = i4 < NT4;
        int ic = v[j] ? i4 : 0;
        q4[j] = eq4[ic];
        s4[j] = es4[ic];
        if (v[j]) {
            atomicAdd(&s_hist[q4[j].x >> 7], 1);
            atomicAdd(&s_hist[q4[j].y >> 7], 1);
            atomicAdd(&s_hist[q4[j].z >> 7], 1);
            atomicAdd(&s_hist[q4[j].w >> 7], 1);
        }
    }
    __syncthreads();

    // exclusive prefix of s_hist -> s_cur, via per-thread 4-sum + wave shfl scan
    int local[4], tsum = 0;
#pragma unroll
    for (int j = 0; j < 4; ++j) {
        int idx = 4 * tid + j;
        local[j] = (idx < NB) ? s_hist[idx] : 0;
        tsum += local[j];
    }
    int inc = tsum;
#pragma unroll
    for (int off = 1; off < 64; off <<= 1) {
        int t = __shfl_up(inc, off);
        if (lane >= off) inc += t;
    }
    if (lane == 63) s_wsum[wv] = inc;
    __syncthreads();
    int wbase = 0;
    for (int w = 0; w < wv; ++w) wbase += s_wsum[w];
    int run = wbase + inc - tsum;
#pragma unroll
    for (int j = 0; j < 4; ++j) {
        int idx = 4 * tid + j;
        if (idx < NB) s_cur[idx] = run;
        run += local[j];
    }
    __syncthreads();

    // reserve global space per non-empty bucket; s_off maps LDS idx -> global idx
    for (int b = tid; b < NB; b += 256) {
        int c = s_hist[b];
        int base = c ? atomicAdd(&cursor[b], c) : 0;
        s_off[b] = b * CAPB + base - s_cur[b];
    }
    __syncthreads();

    // scatter into bucket-sorted LDS stage, computing global dest on the fly
#pragma unroll
    for (int j = 0; j < 4; ++j) {
        if (v[j]) {
            int qs[4] = { q4[j].x, q4[j].y, q4[j].z, q4[j].w };
            int ss[4] = { s4[j].x, s4[j].y, s4[j].z, s4[j].w };
#pragma unroll
            for (int m = 0; m < 4; ++m) {
                int bkt = qs[m] >> 7;
                int idx = atomicAdd(&s_cur[bkt], 1);
                int gpos = idx + s_off[bkt];
                if (gpos >= (bkt + 1) * CAPB) gpos = NB * CAPB;  // dump slot (overflow guard)
                s_rec[idx] = ((unsigned)(qs[m] & (QPB - 1)) << 17) | (unsigned)ss[m];
                s_pos[idx] = gpos;
            }
        }
    }
    __syncthreads();

    // write-out: bucket-contiguous runs -> mostly coalesced
    for (int i = tid; i < tileCount; i += 256)
        slots[s_pos[i]] = s_rec[i];
}

__global__ __launch_bounds__(256) void bucket_kernel(
        const int* __restrict__ cursor,
        const unsigned int* __restrict__ slots,
        const float4* __restrict__ sp4,
        const float* __restrict__ qp,
        float* __restrict__ feats,
        float* __restrict__ psum,
        float* __restrict__ psumsq) {
    __shared__ unsigned int s_sorted[CAPB];   // 18 KB
    __shared__ float qtile[QPB * 3];
    __shared__ int s_cnt[QPB], s_start[QPB], s_cur[QPB];
    __shared__ float s_red1[4][9], s_red2[4][9];

    int tid = threadIdx.x;
    int b = blockIdx.x;
    int cnt = cursor[b];
    if (cnt > CAPB) cnt = CAPB;

    if (tid < QPB) s_cnt[tid] = 0;
    for (int i = tid; i < QPB * 3; i += 256) {
        int g = b * QPB * 3 + i;
        qtile[i] = (g < Q_NODES * 3) ? qp[g] : 0.0f;
    }
    __syncthreads();

    const unsigned int* bslots = slots + b * CAPB;
    // histogram by query-within-bucket (random addresses -> low contention)
    for (int i = tid; i < cnt; i += 256)
        atomicAdd(&s_cnt[bslots[i] >> 17], 1);
    __syncthreads();

    // exclusive scan of 128 counts by wave 0 (2 elements/lane, shfl scan)
    if (tid < 64) {
        int a0 = s_cnt[tid], a1 = s_cnt[64 + tid];
        int i0 = a0, i1 = a1;
#pragma unroll
        for (int off = 1; off < 64; off <<= 1) {
            int t0 = __shfl_up(i0, off); if (tid >= off) i0 += t0;
            int t1 = __shfl_up(i1, off); if (tid >= off) i1 += t1;
        }
        int tot0 = __shfl(i0, 63);
        s_start[tid] = i0 - a0;              s_cur[tid] = i0 - a0;
        s_start[64 + tid] = i1 - a1 + tot0;  s_cur[64 + tid] = i1 - a1 + tot0;
    }
    __syncthreads();

    // counting-sort scatter into LDS
    for (int i = tid; i < cnt; i += 256) {
        unsigned rec = bslots[i];
        int pos = atomicAdd(&s_cur[rec >> 17], 1);
        s_sorted[pos] = rec;
    }
    __syncthreads();

    // per-query register accumulate: thread t owns query t (zero atomics)
    float f[9];
#pragma unroll
    for (int k = 0; k < 9; ++k) f[k] = 0.0f;
    int q = b * QPB + tid;
    if (tid < QPB && q < Q_NODES) {
        float qx = qtile[3 * tid + 0], qy = qtile[3 * tid + 1], qz = qtile[3 * tid + 2];
        float s[12];
#pragma unroll
        for (int k = 0; k < 12; ++k) s[k] = 0.0f;
        int st = s_start[tid], deg = s_cnt[tid];
        for (int j = 0; j < deg; ++j) {
            unsigned rec = s_sorted[st + j];
            float4 sv = sp4[rec & 0x1FFFF];
            float dx = sv.x - qx, dy = sv.y - qy, dz = sv.z - qz;
            float d2 = dx * dx + dy * dy + dz * dz;
            s[0] += 1.0f;
            s[1] += sqrtf(d2);
            s[2] += d2;
            s[3] += sv.x; s[4] += sv.y; s[5] += sv.z;
            s[6] += sv.x * sv.x; s[7] += sv.x * sv.y; s[8] += sv.x * sv.z;
            s[9] += sv.y * sv.y; s[10] += sv.y * sv.z; s[11] += sv.z * sv.z;
        }
        sums_to_feats(s, qx, qy, qz, f);
#pragma unroll
        for (int k = 0; k < 9; ++k) feats[k * Q_NODES + q] = f[k];  // coalesced per k
    }

    // dataset-wide stats: wave reduce -> LDS -> ONE non-atomic partial row per block
    int lane = tid & 63, wv = tid >> 6;
#pragma unroll
    for (int k = 0; k < 9; ++k) {
        float s1 = f[k];
        float s2 = f[k] * f[k];
#pragma unroll
        for (int off = 32; off > 0; off >>= 1) {
            s1 += __shfl_down(s1, off);
            s2 += __shfl_down(s2, off);
        }
        if (lane == 0) { s_red1[wv][k] = s1; s_red2[wv][k] = s2; }
    }
    __syncthreads();
    if (tid < 9) {
        psum[tid * NB + b]   = s_red1[0][tid] + s_red1[1][tid] + s_red1[2][tid] + s_red1[3][tid];
        psumsq[tid * NB + b] = s_red2[0][tid] + s_red2[1][tid] + s_red2[2][tid] + s_red2[3][tid];
    }
}

// single-block tree reduce of per-block partials -> mean / inv_std (double precision)
__global__ __launch_bounds__(256) void stats_reduce_kernel(
        const float* __restrict__ psum,
        const float* __restrict__ psumsq,
        float* __restrict__ norm) {
    __shared__ double w1[4], w2[4];
    int tid = threadIdx.x, lane = tid & 63, wv = tid >> 6;
    for (int k = 0; k < 9; ++k) {
        double a1 = 0.0, a2 = 0.0;
        for (int b = tid; b < NB; b += 256) {
            a1 += (double)psum[k * NB + b];
            a2 += (double)psumsq[k * NB + b];
        }
#pragma unroll
        for (int off = 32; off > 0; off >>= 1) {
            a1 += __shfl_down(a1, off);
            a2 += __shfl_down(a2, off);
        }
        if (lane == 0) { w1[wv] = a1; w2[wv] = a2; }
        __syncthreads();
        if (tid == 0) {
            double S  = w1[0] + w1[1] + w1[2] + w1[3];
            double S2 = w2[0] + w2[1] + w2[2] + w2[3];
            double mean = S / (double)Q_NODES;
            double var = (S2 - S * S / (double)Q_NODES) / (double)(Q_NODES - 1);
            if (var < 0.0) var = 0.0;
            double sd = sqrt(var);
            if (sd < 1e-6) sd = 1.0;
            norm[k] = (float)mean;
            norm[9 + k] = (float)(1.0 / sd);
        }
        __syncthreads();
    }
}

// ============================================================================
// FALLBACK PATH (round-1 algorithm, used only if ws_size too small)
// ============================================================================

__global__ __launch_bounds__(256) void edge_kernel(
        const int* __restrict__ edge,
        const float* __restrict__ sp,
        const float* __restrict__ qp,
        float* __restrict__ acc) {
    int e = blockIdx.x * 256 + threadIdx.x;
    if (e >= N_EDGES) return;
    int q = edge[e];
    int s = edge[N_EDGES + e];
    float sx = sp[3 * s + 0], sy = sp[3 * s + 1], sz = sp[3 * s + 2];
    float qx = qp[3 * q + 0], qy = qp[3 * q + 1], qz = qp[3 * q + 2];
    float dx = sx - qx, dy = sy - qy, dz = sz - qz;
    float d2 = dx * dx + dy * dy + dz * dz;
    atomAddF(acc + 0 * Q_NODES + q, 1.0f);
    atomAddF(acc + 1 * Q_NODES + q, sqrtf(d2));
    atomAddF(acc + 2 * Q_NODES + q, d2);
    atomAddF(acc + 3 * Q_NODES + q, sx);
    atomAddF(acc + 4 * Q_NODES + q, sy);
    atomAddF(acc + 5 * Q_NODES + q, sz);
    atomAddF(acc + 6 * Q_NODES + q, sx * sx);
    atomAddF(acc + 7 * Q_NODES + q, sx * sy);
    atomAddF(acc + 8 * Q_NODES + q, sx * sz);
    atomAddF(acc + 9 * Q_NODES + q, sy * sy);
    atomAddF(acc + 10 * Q_NODES + q, sy * sz);
    atomAddF(acc + 11 * Q_NODES + q, sz * sz);
}

__global__ __launch_bounds__(256) void finalize_kernel(
        const float* __restrict__ acc,
        const float* __restrict__ qp,
        float* __restrict__ feats,
        double* __restrict__ stats) {
    int q = blockIdx.x * 256 + threadIdx.x;
    float f[9];
#pragma unroll
    for (int k = 0; k < 9; ++k) f[k] = 0.0f;
    if (q < Q_NODES) {
        float s[12];
#pragma unroll
        for (int k = 0; k < 12; ++k) s[k] = acc[k * Q_NODES + q];
        float qx = qp[3 * q + 0], qy = qp[3 * q + 1], qz = qp[3 * q + 2];
        sums_to_feats(s, qx, qy, qz, f);
#pragma unroll
        for (int k = 0; k < 9; ++k) feats[k * Q_NODES + q] = f[k];
    }
    int lane = threadIdx.x & 63;
#pragma unroll
    for (int k = 0; k < 9; ++k) {
        float s1 = f[k];
        float s2 = f[k] * f[k];
#pragma unroll
        for (int off = 32; off > 0; off >>= 1) {
            s1 += __shfl_down(s1, off);
            s2 += __shfl_down(s2, off);
        }
        if (lane == 0) {
            atomicAdd(&stats[k], (double)s1);
            atomicAdd(&stats[9 + k], (double)s2);
        }
    }
}

__global__ void stats_kernel(const double* __restrict__ stats,
                             float* __restrict__ norm) {
    int k = threadIdx.x;
    if (k < 9) {
        double S = stats[k], S2 = stats[9 + k];
        double mean = S / (double)Q_NODES;
        double var = (S2 - S * S / (double)Q_NODES) / (double)(Q_NODES - 1);
        if (var < 0.0) var = 0.0;
        double sd = sqrt(var);
        if (sd < 1e-6) sd = 1.0;
        norm[k] = (float)mean;
        norm[9 + k] = (float)(1.0 / sd);
    }
}

// ============================================================================
// Shared tail kernel
// ============================================================================

__global__ __launch_bounds__(256) void mlp_kernel(
        const float* __restrict__ feats,
        const float* __restrict__ norm,
        const float* __restrict__ W1, const float* __restrict__ b1,
        const float* __restrict__ W2, const float* __restrict__ b2,
        float* __restrict__ out) {
    __shared__ float sm[576 + 64 + 8192 + 128 + 18];
    float* sW1 = sm;                 // [64][9]
    float* sB1 = sm + 576;           // [64]
    float* sW2 = sm + 640;           // [128][64]
    float* sB2 = sm + 8832;          // [128]
    float* sNorm = sm + 8960;        // [18]

    for (int i = threadIdx.x; i < 576; i += 256) sW1[i] = W1[i];
    if (threadIdx.x < 64) sB1[threadIdx.x] = b1[threadIdx.x];
    for (int i = threadIdx.x; i < 8192; i += 256) sW2[i] = W2[i];
    if (threadIdx.x < 128) sB2[threadIdx.x] = b2[threadIdx.x];
    if (threadIdx.x < 18) sNorm[threadIdx.x] = norm[threadIdx.x];
    __syncthreads();

    int q = blockIdx.x * 256 + threadIdx.x;
    bool valid = q < Q_NODES;
    int qq = valid ? q : 0;

    float f[9];
#pragma unroll
    for (int k = 0; k < 9; ++k)
        f[k] = (feats[k * Q_NODES + qq] - sNorm[k]) * sNorm[9 + k];

    float h[64];
#pragma unroll
    for (int j = 0; j < 64; ++j) {
        float a = sB1[j];
#pragma unroll
        for (int k = 0; k < 9; ++k) a = fmaf(f[k], sW1[j * 9 + k], a);
        h[j] = fmaxf(a, 0.0f);
    }

    if (!valid) return;
    float* op = out + (size_t)q * 128;
#pragma unroll 1
    for (int o = 0; o < 128; o += 4) {
        float a0 = sB2[o + 0], a1 = sB2[o + 1], a2 = sB2[o + 2], a3 = sB2[o + 3];
#pragma unroll
        for (int j = 0; j < 64; j += 4) {
            float4 w0 = *(const float4*)&sW2[(o + 0) * 64 + j];
            float4 w1 = *(const float4*)&sW2[(o + 1) * 64 + j];
            float4 w2 = *(const float4*)&sW2[(o + 2) * 64 + j];
            float4 w3 = *(const float4*)&sW2[(o + 3) * 64 + j];
            float h0 = h[j], h1 = h[j + 1], h2 = h[j + 2], h3 = h[j + 3];
            a0 = fmaf(h0, w0.x, a0); a0 = fmaf(h1, w0.y, a0); a0 = fmaf(h2, w0.z, a0); a0 = fmaf(h3, w0.w, a0);
            a1 = fmaf(h0, w1.x, a1); a1 = fmaf(h1, w1.y, a1); a1 = fmaf(h2, w1.z, a1); a1 = fmaf(h3, w1.w, a1);
            a2 = fmaf(h0, w2.x, a2); a2 = fmaf(h1, w2.y, a2); a2 = fmaf(h2, w2.z, a2); a2 = fmaf(h3, w2.w, a2);
            a3 = fmaf(h0, w3.x, a3); a3 = fmaf(h1, w3.y, a3); a3 = fmaf(h2, w3.z, a3); a3 = fmaf(h3, w3.w, a3);
        }
        float4 vv = make_float4(a0, a1, a2, a3);
        *(float4*)(op + o) = vv;
    }
}

// ============================================================================

extern "C" void kernel_launch(void* const* d_in, const int* in_sizes, int n_in,
                              void* d_out, int out_size, void* d_ws, size_t ws_size,
                              hipStream_t stream) {
    const float* sp   = (const float*)d_in[0];
    const float* qp   = (const float*)d_in[1];
    const int*   edge = (const int*)d_in[2];
    const float* W1   = (const float*)d_in[3];
    const float* b1   = (const float*)d_in[4];
    const float* W2   = (const float*)d_in[5];
    const float* b2   = (const float*)d_in[6];
    float* out = (float*)d_out;
    char* ws = (char*)d_ws;

    if (ws_size >= F_WS_NEED) {
        int*          cursor = (int*)(ws + F_CURSOR_OFF);
        float*        norm   = (float*)(ws + F_NORM_OFF);
        float*        psum   = (float*)(ws + F_PSUM_OFF);
        float*        psumsq = (float*)(ws + F_PSUMSQ_OFF);
        float*        feats  = (float*)(ws + F_FEATS_OFF);
        float4*       sp4    = (float4*)(ws + F_SP4_OFF);
        unsigned int* slots  = (unsigned int*)(ws + F_SLOTS_OFF);

        hipMemsetAsync(ws, 0, F_ZERO_BYTES, stream);
        pad_kernel<<<(S_NODES + 255) / 256, 256, 0, stream>>>(sp, sp4);
        partition_kernel<<<(N_EDGES + TILE - 1) / TILE, 256, 0, stream>>>(edge, cursor, slots);
        bucket_kernel<<<NB, 256, 0, stream>>>(cursor, slots, sp4, qp, feats, psum, psumsq);
        stats_reduce_kernel<<<1, 256, 0, stream>>>(psum, psumsq, norm);
        mlp_kernel<<<(Q_NODES + 255) / 256, 256, 0, stream>>>(feats, norm, W1, b1, W2, b2, out);
    } else {
        float*  acc   = (float*)(ws + B_ACC_OFF);
        double* stats = (double*)(ws + B_STATS_OFF);
        float*  norm  = (float*)(ws + B_NORM_OFF);
        float*  feats = (float*)(ws + B_FEATS_OFF);

        hipMemsetAsync(ws, 0, B_ZERO_BYTES, stream);
        edge_kernel<<<N_EDGES / 256, 256, 0, stream>>>(edge, sp, qp, acc);
        finalize_kernel<<<(Q_NODES + 255) / 256, 256, 0, stream>>>(acc, qp, feats, stats);
        stats_kernel<<<1, 64, 0, stream>>>(stats, norm);
        mlp_kernel<<<(Q_NODES + 255) / 256, 256, 0, stream>>>(feats, norm, W1, b1, W2, b2, out);
    }
}

// Round 6
// 206.551 us; speedup vs baseline: 10.5331x; 1.2468x over previous
//
#include <hip/hip_runtime.h>
#include <math.h>

#define Q_NODES 100000
#define S_NODES 100000
#define N_EDGES 3200000
#define HIDDEN 64
#define OUT_DIM 128

// ---------- bucket partition parameters ----------
#define QPB   128                    // queries per bucket (bucket = q >> 7)
#define NB    782                    // ceil(Q_NODES / QPB)
#define CAPB  4608                   // bucket capacity: mean 4096, +8 sigma
#define TILE  4096                   // edges per partition block
#define NT4   (N_EDGES / 4)          // int4 count per edge row

// ---------- FAST-PATH workspace layout (bytes) ----------
#define F_CURSOR_OFF 0
#define F_NORM_OFF   3200
#define F_PSUM_OFF   3328
#define F_PSUMSQ_OFF 31488
#define F_FEATS_OFF  59648
#define F_SP4_OFF    3659648
#define F_SLOTS_OFF  5259648
#define F_ZERO_BYTES 3200            // cursor only
#define F_WS_NEED    (5259648ull + (unsigned long long)(NB * CAPB + 1) * 4)

// ---------- FALLBACK workspace layout (round-1 algorithm) ----------
#define B_ACC_OFF    0
#define B_STATS_OFF  4800000
#define B_NORM_OFF   4800144
#define B_FEATS_OFF  4800224
#define B_ZERO_BYTES 4800144

__device__ __forceinline__ void atomAddF(float* p, float v) {
#if defined(__gfx950__) || defined(__gfx942__) || defined(__gfx90a__)
    unsafeAtomicAdd(p, v);
#else
    atomicAdd(p, v);
#endif
}

// ============================================================================
// Shared device helpers
// ============================================================================

__device__ __forceinline__ void eig3_sym(
        float a00, float a01, float a02, float a11, float a12, float a22,
        float& e1, float& e2, float& e3) {
    float p1 = a01 * a01 + a02 * a02 + a12 * a12;
    float qm = (a00 + a11 + a22) * (1.0f / 3.0f);
    float b00 = a00 - qm, b11 = a11 - qm, b22 = a22 - qm;
    float p2 = b00 * b00 + b11 * b11 + b22 * b22 + 2.0f * p1;
    if (p2 <= 1e-24f) {
        e1 = qm; e2 = qm; e3 = qm;
    } else {
        float p = sqrtf(p2 * (1.0f / 6.0f));
        float invp = 1.0f / p;
        float c00 = b00 * invp, c11 = b11 * invp, c22 = b22 * invp;
        float c01 = a01 * invp, c02 = a02 * invp, c12 = a12 * invp;
        float detB = c00 * (c11 * c22 - c12 * c12)
                   - c01 * (c01 * c22 - c12 * c02)
                   + c02 * (c01 * c12 - c11 * c02);
        float r = 0.5f * detB;
        r = fminf(fmaxf(r, -1.0f), 1.0f);
        float phi = acosf(r) * (1.0f / 3.0f);
        e1 = qm + 2.0f * p * cosf(phi);
        e3 = qm + 2.0f * p * cosf(phi + 2.0943951023931953f); // +2pi/3
        e2 = 3.0f * qm - e1 - e3;
    }
}

// sums: n,sumd,sumd2,sx,sy,sz,xx,xy,xz,yy,yz,zz -> 9 features
__device__ __forceinline__ void sums_to_feats(
        const float* s, float qx, float qy, float qz, float* f) {
    float n = s[0];
#pragma unroll
    for (int k = 0; k < 9; ++k) f[k] = 0.0f;
    if (n > 0.0f) {
        float inv = 1.0f / n;
        float Davg = s[1] * inv;
        float Dvar = fmaxf(s[2] * inv - Davg * Davg, 0.0f);
        float cx = s[3] * inv, cy = s[4] * inv, cz = s[5] * inv;
        float a00 = fmaxf(s[6] * inv - cx * cx, 0.0f);
        float a01 = s[7] * inv - cx * cy;
        float a02 = s[8] * inv - cx * cz;
        float a11 = fmaxf(s[9] * inv - cy * cy, 0.0f);
        float a12 = s[10] * inv - cy * cz;
        float a22 = fmaxf(s[11] * inv - cz * cz, 0.0f);
        float e1, e2, e3;
        eig3_sym(a00, a01, a02, a11, a12, a22, e1, e2, e3);
        f[0] = n; f[1] = Davg; f[2] = Dvar;
        f[3] = cx - qx; f[4] = cy - qy; f[5] = cz - qz;
        f[6] = e1; f[7] = e2; f[8] = e3;
    }
}

// ============================================================================
// FAST PATH
// ============================================================================

__global__ __launch_bounds__(256) void pad_kernel(
        const float* __restrict__ sp, float4* __restrict__ sp4) {
    int i = blockIdx.x * 256 + threadIdx.x;
    if (i < S_NODES) sp4[i] = make_float4(sp[3 * i], sp[3 * i + 1], sp[3 * i + 2], 0.0f);
}

__global__ __launch_bounds__(256) void partition_kernel(
        const int* __restrict__ edge,
        int* __restrict__ cursor,
        unsigned int* __restrict__ slots) {
    __shared__ unsigned int s_rec[TILE];   // 16 KB: packed records, bucket-sorted
    __shared__ int s_pos[TILE];            // 16 KB: global dest index per record
    __shared__ int s_hist[NB];
    __shared__ int s_cur[NB];              // pref during scan, then scatter cursor
    __shared__ int s_off[NB];              // bkt*CAPB + base - pref
    __shared__ int s_wsum[4];

    int tid = threadIdx.x;
    int lane = tid & 63, wv = tid >> 6;
    int tileStart = blockIdx.x * TILE;
    int tileCount = N_EDGES - tileStart;
    if (tileCount > TILE) tileCount = TILE;

    for (int b = tid; b < NB; b += 256) s_hist[b] = 0;
    __syncthreads();

    const int4* eq4 = (const int4*)edge;
    const int4* es4 = (const int4*)(edge + N_EDGES);
    int base4 = blockIdx.x * (TILE / 4);
    int4 q4[4], s4[4];
    bool v[4];
#pragma unroll
    for (int j = 0; j < 4; ++j) {
        int i4 = base4 + tid + j * 256;
        v[j] = i4 < NT4;
        int ic = v[j] ? i4 : 0;
        q4[j] = eq4[ic];
        s4[j] = es4[ic];
        if (v[j]) {
            atomicAdd(&s_hist[q4[j].x >> 7], 1);
            atomicAdd(&s_hist[q4[j].y >> 7], 1);
            atomicAdd(&s_hist[q4[j].z >> 7], 1);
            atomicAdd(&s_hist[q4[j].w >> 7], 1);
        }
    }
    __syncthreads();

    // exclusive prefix of s_hist -> s_cur, via per-thread 4-sum + wave shfl scan
    int local[4], tsum = 0;
#pragma unroll
    for (int j = 0; j < 4; ++j) {
        int idx = 4 * tid + j;
        local[j] = (idx < NB) ? s_hist[idx] : 0;
        tsum += local[j];
    }
    int inc = tsum;
#pragma unroll
    for (int off = 1; off < 64; off <<= 1) {
        int t = __shfl_up(inc, off);
        if (lane >= off) inc += t;
    }
    if (lane == 63) s_wsum[wv] = inc;
    __syncthreads();
    int wbase = 0;
    for (int w = 0; w < wv; ++w) wbase += s_wsum[w];
    int run = wbase + inc - tsum;
#pragma unroll
    for (int j = 0; j < 4; ++j) {
        int idx = 4 * tid + j;
        if (idx < NB) s_cur[idx] = run;
        run += local[j];
    }
    __syncthreads();

    // reserve global space per non-empty bucket; s_off maps LDS idx -> global idx
    for (int b = tid; b < NB; b += 256) {
        int c = s_hist[b];
        int base = c ? atomicAdd(&cursor[b], c) : 0;
        s_off[b] = b * CAPB + base - s_cur[b];
    }
    __syncthreads();

    // scatter into bucket-sorted LDS stage, computing global dest on the fly
#pragma unroll
    for (int j = 0; j < 4; ++j) {
        if (v[j]) {
            int qs[4] = { q4[j].x, q4[j].y, q4[j].z, q4[j].w };
            int ss[4] = { s4[j].x, s4[j].y, s4[j].z, s4[j].w };
#pragma unroll
            for (int m = 0; m < 4; ++m) {
                int bkt = qs[m] >> 7;
                int idx = atomicAdd(&s_cur[bkt], 1);
                int gpos = idx + s_off[bkt];
                if (gpos >= (bkt + 1) * CAPB) gpos = NB * CAPB;  // dump slot (overflow guard)
                s_rec[idx] = ((unsigned)(qs[m] & (QPB - 1)) << 17) | (unsigned)ss[m];
                s_pos[idx] = gpos;
            }
        }
    }
    __syncthreads();

    // write-out: bucket-contiguous runs -> mostly coalesced
    for (int i = tid; i < tileCount; i += 256)
        slots[s_pos[i]] = s_rec[i];
}

__global__ __launch_bounds__(256) void bucket_kernel(
        const int* __restrict__ cursor,
        const unsigned int* __restrict__ slots,
        const float4* __restrict__ sp4,
        const float* __restrict__ qp,
        float* __restrict__ feats,
        float* __restrict__ psum,
        float* __restrict__ psumsq) {
    __shared__ unsigned int s_sorted[CAPB];   // 18 KB
    __shared__ float qtile[QPB * 3];
    __shared__ int s_cnt[QPB], s_start[QPB], s_cur[QPB];
    __shared__ float s_red1[4][9], s_red2[4][9];

    int tid = threadIdx.x;
    int b = blockIdx.x;
    int cnt = cursor[b];
    if (cnt > CAPB) cnt = CAPB;

    if (tid < QPB) s_cnt[tid] = 0;
    for (int i = tid; i < QPB * 3; i += 256) {
        int g = b * QPB * 3 + i;
        qtile[i] = (g < Q_NODES * 3) ? qp[g] : 0.0f;
    }
    __syncthreads();

    const unsigned int* bslots = slots + b * CAPB;
    // histogram by query-within-bucket (random addresses -> low contention)
    for (int i = tid; i < cnt; i += 256)
        atomicAdd(&s_cnt[bslots[i] >> 17], 1);
    __syncthreads();

    // exclusive scan of 128 counts by wave 0 (2 elements/lane, shfl scan)
    if (tid < 64) {
        int a0 = s_cnt[tid], a1 = s_cnt[64 + tid];
        int i0 = a0, i1 = a1;
#pragma unroll
        for (int off = 1; off < 64; off <<= 1) {
            int t0 = __shfl_up(i0, off); if (tid >= off) i0 += t0;
            int t1 = __shfl_up(i1, off); if (tid >= off) i1 += t1;
        }
        int tot0 = __shfl(i0, 63);
        s_start[tid] = i0 - a0;              s_cur[tid] = i0 - a0;
        s_start[64 + tid] = i1 - a1 + tot0;  s_cur[64 + tid] = i1 - a1 + tot0;
    }
    __syncthreads();

    // counting-sort scatter into LDS
    for (int i = tid; i < cnt; i += 256) {
        unsigned rec = bslots[i];
        int pos = atomicAdd(&s_cur[rec >> 17], 1);
        s_sorted[pos] = rec;
    }
    __syncthreads();

    // per-query register accumulate: thread t owns query t (zero atomics)
    float f[9];
#pragma unroll
    for (int k = 0; k < 9; ++k) f[k] = 0.0f;
    int q = b * QPB + tid;
    if (tid < QPB && q < Q_NODES) {
        float qx = qtile[3 * tid + 0], qy = qtile[3 * tid + 1], qz = qtile[3 * tid + 2];
        float s[12];
#pragma unroll
        for (int k = 0; k < 12; ++k) s[k] = 0.0f;
        int st = s_start[tid], deg = s_cnt[tid];
        for (int j = 0; j < deg; ++j) {
            unsigned rec = s_sorted[st + j];
            float4 sv = sp4[rec & 0x1FFFF];
            float dx = sv.x - qx, dy = sv.y - qy, dz = sv.z - qz;
            float d2 = dx * dx + dy * dy + dz * dz;
            s[0] += 1.0f;
            s[1] += sqrtf(d2);
            s[2] += d2;
            s[3] += sv.x; s[4] += sv.y; s[5] += sv.z;
            s[6] += sv.x * sv.x; s[7] += sv.x * sv.y; s[8] += sv.x * sv.z;
            s[9] += sv.y * sv.y; s[10] += sv.y * sv.z; s[11] += sv.z * sv.z;
        }
        sums_to_feats(s, qx, qy, qz, f);
#pragma unroll
        for (int k = 0; k < 9; ++k) feats[k * Q_NODES + q] = f[k];  // coalesced per k
    }

    // dataset-wide stats: wave reduce -> LDS -> ONE non-atomic partial row per block
    int lane = tid & 63, wv = tid >> 6;
#pragma unroll
    for (int k = 0; k < 9; ++k) {
        float s1 = f[k];
        float s2 = f[k] * f[k];
#pragma unroll
        for (int off = 32; off > 0; off >>= 1) {
            s1 += __shfl_down(s1, off);
            s2 += __shfl_down(s2, off);
        }
        if (lane == 0) { s_red1[wv][k] = s1; s_red2[wv][k] = s2; }
    }
    __syncthreads();
    if (tid < 9) {
        psum[tid * NB + b]   = s_red1[0][tid] + s_red1[1][tid] + s_red1[2][tid] + s_red1[3][tid];
        psumsq[tid * NB + b] = s_red2[0][tid] + s_red2[1][tid] + s_red2[2][tid] + s_red2[3][tid];
    }
}

// single-block tree reduce of per-block partials -> mean / inv_std (double precision)
__global__ __launch_bounds__(256) void stats_reduce_kernel(
        const float* __restrict__ psum,
        const float* __restrict__ psumsq,
        float* __restrict__ norm) {
    __shared__ double w1[4], w2[4];
    int tid = threadIdx.x, lane = tid & 63, wv = tid >> 6;
    for (int k = 0; k < 9; ++k) {
        double a1 = 0.0, a2 = 0.0;
        for (int b = tid; b < NB; b += 256) {
            a1 += (double)psum[k * NB + b];
            a2 += (double)psumsq[k * NB + b];
        }
#pragma unroll
        for (int off = 32; off > 0; off >>= 1) {
            a1 += __shfl_down(a1, off);
            a2 += __shfl_down(a2, off);
        }
        if (lane == 0) { w1[wv] = a1; w2[wv] = a2; }
        __syncthreads();
        if (tid == 0) {
            double S  = w1[0] + w1[1] + w1[2] + w1[3];
            double S2 = w2[0] + w2[1] + w2[2] + w2[3];
            double mean = S / (double)Q_NODES;
            double var = (S2 - S * S / (double)Q_NODES) / (double)(Q_NODES - 1);
            if (var < 0.0) var = 0.0;
            double sd = sqrt(var);
            if (sd < 1e-6) sd = 1.0;
            norm[k] = (float)mean;
            norm[9 + k] = (float)(1.0 / sd);
        }
        __syncthreads();
    }
}

// ============================================================================
// MLP: tiled GEMM. Block = 128 queries x 64 outputs (o-half).
// Layer-1 h-tile -> LDS [k][q]; W2^T half -> LDS [k][o]; 8q x 4o regs/thread.
// ============================================================================

__global__ __launch_bounds__(256, 3) void mlp_kernel(
        const float* __restrict__ feats,
        const float* __restrict__ norm,
        const float* __restrict__ W1, const float* __restrict__ b1,
        const float* __restrict__ W2, const float* __restrict__ b2,
        float* __restrict__ out) {
    __shared__ float sW1[576];        // [64][9]
    __shared__ float sB1[64];
    __shared__ float sB2[64];         // this o-half
    __shared__ float sNorm[18];
    __shared__ float w2t[64 * 64];    // [k][o]  (o within half)
    __shared__ float ht[64 * 128];    // [k][q]

    int tid = threadIdx.x;
    int blk_q = blockIdx.x >> 1;
    int oh = (blockIdx.x & 1) * 64;   // output half offset

    for (int i = tid; i < 576; i += 256) sW1[i] = W1[i];
    if (tid < 64) { sB1[tid] = b1[tid]; sB2[tid] = b2[oh + tid]; }
    if (tid < 18) sNorm[tid] = norm[tid];
    __syncthreads();

    // W2^T staging: thread owns column o = tid&63, k-chunk of 16.
    // LDS write banks: per iter k fixed, lanes span o -> 2-way (free).
    {
        int o = tid & 63, kc = (tid >> 6) * 16;
#pragma unroll
        for (int j = 0; j < 16; ++j) {
            int k = kc + j;
            w2t[k * 64 + o] = W2[(oh + o) * 64 + k];
        }
    }

    // Layer 1: thread (q = tid&127, half = tid>>7) computes 32 h-rows for its q.
    {
        int q = tid & 127, half = tid >> 7;
        int qg = blk_q * 128 + q;
        int qc = qg < Q_NODES ? qg : Q_NODES - 1;
        float f[9];
#pragma unroll
        for (int k = 0; k < 9; ++k)
            f[k] = (feats[k * Q_NODES + qc] - sNorm[k]) * sNorm[9 + k];
#pragma unroll 4
        for (int j = 0; j < 32; ++j) {
            int ko = half * 32 + j;
            float a = sB1[ko];
#pragma unroll
            for (int kf = 0; kf < 9; ++kf) a = fmaf(f[kf], sW1[ko * 9 + kf], a);
            ht[ko * 128 + q] = fmaxf(a, 0.0f);   // banks: lanes span q -> free
        }
    }
    __syncthreads();

    // Layer 2: thread tile 8q x 4o. qt in [0,16), ot in [0,16).
    int qt = tid >> 4, ot = tid & 15;
    int q0 = qt * 8, o0 = ot * 4;
    float acc[8][4];
#pragma unroll
    for (int i = 0; i < 8; ++i)
#pragma unroll
        for (int j = 0; j < 4; ++j) acc[i][j] = 0.0f;

#pragma unroll 4
    for (int k = 0; k < 64; ++k) {
        float4 h0 = *(const float4*)&ht[k * 128 + q0];       // 4-addr broadcast, free
        float4 h1 = *(const float4*)&ht[k * 128 + q0 + 4];
        float4 w  = *(const float4*)&w2t[k * 64 + o0];       // 2-way, free
        float hh[8] = { h0.x, h0.y, h0.z, h0.w, h1.x, h1.y, h1.z, h1.w };
#pragma unroll
        for (int i = 0; i < 8; ++i) {
            acc[i][0] = fmaf(hh[i], w.x, acc[i][0]);
            acc[i][1] = fmaf(hh[i], w.y, acc[i][1]);
            acc[i][2] = fmaf(hh[i], w.z, acc[i][2]);
            acc[i][3] = fmaf(hh[i], w.w, acc[i][3]);
        }
    }

    // Epilogue: +bias, coalesced stores (16 lanes x 16 B = 256 B contiguous runs)
    float4 bb = *(const float4*)&sB2[o0];
#pragma unroll
    for (int i = 0; i < 8; ++i) {
        int qg = blk_q * 128 + q0 + i;
        if (qg < Q_NODES) {
            float4 v = make_float4(acc[i][0] + bb.x, acc[i][1] + bb.y,
                                   acc[i][2] + bb.z, acc[i][3] + bb.w);
            *(float4*)(out + (size_t)qg * 128 + oh + o0) = v;
        }
    }
}

// ============================================================================
// FALLBACK PATH (round-1 algorithm, used only if ws_size too small)
// ============================================================================

__global__ __launch_bounds__(256) void edge_kernel(
        const int* __restrict__ edge,
        const float* __restrict__ sp,
        const float* __restrict__ qp,
        float* __restrict__ acc) {
    int e = blockIdx.x * 256 + threadIdx.x;
    if (e >= N_EDGES) return;
    int q = edge[e];
    int s = edge[N_EDGES + e];
    float sx = sp[3 * s + 0], sy = sp[3 * s + 1], sz = sp[3 * s + 2];
    float qx = qp[3 * q + 0], qy = qp[3 * q + 1], qz = qp[3 * q + 2];
    float dx = sx - qx, dy = sy - qy, dz = sz - qz;
    float d2 = dx * dx + dy * dy + dz * dz;
    atomAddF(acc + 0 * Q_NODES + q, 1.0f);
    atomAddF(acc + 1 * Q_NODES + q, sqrtf(d2));
    atomAddF(acc + 2 * Q_NODES + q, d2);
    atomAddF(acc + 3 * Q_NODES + q, sx);
    atomAddF(acc + 4 * Q_NODES + q, sy);
    atomAddF(acc + 5 * Q_NODES + q, sz);
    atomAddF(acc + 6 * Q_NODES + q, sx * sx);
    atomAddF(acc + 7 * Q_NODES + q, sx * sy);
    atomAddF(acc + 8 * Q_NODES + q, sx * sz);
    atomAddF(acc + 9 * Q_NODES + q, sy * sy);
    atomAddF(acc + 10 * Q_NODES + q, sy * sz);
    atomAddF(acc + 11 * Q_NODES + q, sz * sz);
}

__global__ __launch_bounds__(256) void finalize_kernel(
        const float* __restrict__ acc,
        const float* __restrict__ qp,
        float* __restrict__ feats,
        double* __restrict__ stats) {
    int q = blockIdx.x * 256 + threadIdx.x;
    float f[9];
#pragma unroll
    for (int k = 0; k < 9; ++k) f[k] = 0.0f;
    if (q < Q_NODES) {
        float s[12];
#pragma unroll
        for (int k = 0; k < 12; ++k) s[k] = acc[k * Q_NODES + q];
        float qx = qp[3 * q + 0], qy = qp[3 * q + 1], qz = qp[3 * q + 2];
        sums_to_feats(s, qx, qy, qz, f);
#pragma unroll
        for (int k = 0; k < 9; ++k) feats[k * Q_NODES + q] = f[k];
    }
    int lane = threadIdx.x & 63;
#pragma unroll
    for (int k = 0; k < 9; ++k) {
        float s1 = f[k];
        float s2 = f[k] * f[k];
#pragma unroll
        for (int off = 32; off > 0; off >>= 1) {
            s1 += __shfl_down(s1, off);
            s2 += __shfl_down(s2, off);
        }
        if (lane == 0) {
            atomicAdd(&stats[k], (double)s1);
            atomicAdd(&stats[9 + k], (double)s2);
        }
    }
}

__global__ void stats_kernel(const double* __restrict__ stats,
                             float* __restrict__ norm) {
    int k = threadIdx.x;
    if (k < 9) {
        double S = stats[k], S2 = stats[9 + k];
        double mean = S / (double)Q_NODES;
        double var = (S2 - S * S / (double)Q_NODES) / (double)(Q_NODES - 1);
        if (var < 0.0) var = 0.0;
        double sd = sqrt(var);
        if (sd < 1e-6) sd = 1.0;
        norm[k] = (float)mean;
        norm[9 + k] = (float)(1.0 / sd);
    }
}

// ============================================================================

extern "C" void kernel_launch(void* const* d_in, const int* in_sizes, int n_in,
                              void* d_out, int out_size, void* d_ws, size_t ws_size,
                              hipStream_t stream) {
    const float* sp   = (const float*)d_in[0];
    const float* qp   = (const float*)d_in[1];
    const int*   edge = (const int*)d_in[2];
    const float* W1   = (const float*)d_in[3];
    const float* b1   = (const float*)d_in[4];
    const float* W2   = (const float*)d_in[5];
    const float* b2   = (const float*)d_in[6];
    float* out = (float*)d_out;
    char* ws = (char*)d_ws;

    if (ws_size >= F_WS_NEED) {
        int*          cursor = (int*)(ws + F_CURSOR_OFF);
        float*        norm   = (float*)(ws + F_NORM_OFF);
        float*        psum   = (float*)(ws + F_PSUM_OFF);
        float*        psumsq = (float*)(ws + F_PSUMSQ_OFF);
        float*        feats  = (float*)(ws + F_FEATS_OFF);
        float4*       sp4    = (float4*)(ws + F_SP4_OFF);
        unsigned int* slots  = (unsigned int*)(ws + F_SLOTS_OFF);

        hipMemsetAsync(ws, 0, F_ZERO_BYTES, stream);
        pad_kernel<<<(S_NODES + 255) / 256, 256, 0, stream>>>(sp, sp4);
        partition_kernel<<<(N_EDGES + TILE - 1) / TILE, 256, 0, stream>>>(edge, cursor, slots);
        bucket_kernel<<<NB, 256, 0, stream>>>(cursor, slots, sp4, qp, feats, psum, psumsq);
        stats_reduce_kernel<<<1, 256, 0, stream>>>(psum, psumsq, norm);
        mlp_kernel<<<NB * 2, 256, 0, stream>>>(feats, norm, W1, b1, W2, b2, out);
    } else {
        float*  acc   = (float*)(ws + B_ACC_OFF);
        double* stats = (double*)(ws + B_STATS_OFF);
        float*  norm  = (float*)(ws + B_NORM_OFF);
        float*  feats = (float*)(ws + B_FEATS_OFF);

        hipMemsetAsync(ws, 0, B_ZERO_BYTES, stream);
        edge_kernel<<<N_EDGES / 256, 256, 0, stream>>>(edge, sp, qp, acc);
        finalize_kernel<<<(Q_NODES + 255) / 256, 256, 0, stream>>>(acc, qp, feats, stats);
        stats_kernel<<<1, 64, 0, stream>>>(stats, norm);
        mlp_kernel<<<NB * 2, 256, 0, stream>>>(feats, norm, W1, b1, W2, b2, out);
    }
}